// Round 5
// baseline (555.470 us; speedup 1.0000x reference)
//
#include <hip/hip_runtime.h>

// Problem constants (fixed by the reference)
#define N_SRNA  20000
#define N_MRNA  100000
#define FDIM    128
#define NE      1000000
#define NQ      500000
#define NDST_ALL (N_MRNA + N_SRNA)   // 120000 combined dst nodes (mrna first, then srna)

// Buckets: mrna dsts in 512-wide buckets, srna dsts in 128-wide buckets
#define NB_M 196                      // 100000 / 512 rounded up
#define NB_S 157                      // 20000 / 128 rounded up
#define NB   (NB_M + NB_S)            // 353
#define NB_Q 196                      // query buckets over mrna cols (512-wide)

typedef __attribute__((ext_vector_type(8))) short bf16x8;
typedef __attribute__((ext_vector_type(4))) float f32x4;

__device__ __forceinline__ unsigned short f2bf(float f) {
    unsigned int u = __float_as_uint(f);
    unsigned int r = (u + 0x7fffu + ((u >> 16) & 1u)) >> 16;   // RNE
    return (unsigned short)r;
}
__device__ __forceinline__ float bf2f(unsigned short h) {
    return __uint_as_float((unsigned int)h << 16);
}

// ---------------------------------------------------------------------------
// Bucketed CSR build for edges (unchanged from round 4)
// ---------------------------------------------------------------------------

__global__ __launch_bounds__(256) void k_bhist(const int* __restrict__ dst_sm,
                                               const int* __restrict__ dst_ms,
                                               int* __restrict__ bcnt) {
    __shared__ int lh[NB];
    for (int i = threadIdx.x; i < NB; i += 256) lh[i] = 0;
    __syncthreads();
    int i0 = blockIdx.x * 4096;
#pragma unroll
    for (int j = 0; j < 16; ++j) {
        int i = i0 + j * 256 + threadIdx.x;
        if (i < NE) {
            atomicAdd(&lh[dst_sm[i] >> 9], 1);
        } else if (i < 2 * NE) {
            atomicAdd(&lh[NB_M + (dst_ms[i - NE] >> 7)], 1);
        }
    }
    __syncthreads();
    for (int i = threadIdx.x; i < NB; i += 256)
        if (lh[i]) atomicAdd(&bcnt[i], lh[i]);
}

__global__ __launch_bounds__(512) void k_bscan(const int* __restrict__ bcnt,
                                               int* __restrict__ bbase,
                                               int* __restrict__ bcur,
                                               int* __restrict__ ptr_end) {
    __shared__ int s[512];
    int t = threadIdx.x;
    int v = (t < NB) ? bcnt[t] : 0;
    s[t] = v;
    __syncthreads();
    for (int off = 1; off < 512; off <<= 1) {
        int x = (t >= off) ? s[t - off] : 0;
        __syncthreads();
        s[t] += x;
        __syncthreads();
    }
    if (t < NB) { int ex = s[t] - v; bbase[t] = ex; bcur[t] = ex; }
    if (t == 0) { bbase[NB] = 2 * NE; *ptr_end = 2 * NE; }
}

__global__ __launch_bounds__(256) void k_bscatter(const int* __restrict__ src_sm,
                                                  const int* __restrict__ dst_sm,
                                                  const int* __restrict__ src_ms,
                                                  const int* __restrict__ dst_ms,
                                                  int* __restrict__ bcur,
                                                  unsigned int* __restrict__ recs) {
    __shared__ int lh[NB], gb[NB], lc[NB];
    int t = threadIdx.x;
    for (int i = t; i < NB; i += 256) { lh[i] = 0; lc[i] = 0; }
    __syncthreads();
    unsigned int rec[16];
    int bk[16];
    int i0 = blockIdx.x * 4096;
#pragma unroll
    for (int j = 0; j < 16; ++j) {
        int i = i0 + j * 256 + t;
        int b = -1; unsigned int r = 0;
        if (i < NE) {
            int d = dst_sm[i];
            b = d >> 9;
            r = ((unsigned int)(d - (b << 9)) << 17) | (unsigned int)src_sm[i];
        } else if (i < 2 * NE) {
            int jj = i - NE;
            int d = dst_ms[jj];
            int bs = d >> 7;
            b = NB_M + bs;
            r = ((unsigned int)(d - (bs << 7)) << 17) | (unsigned int)src_ms[jj];
        }
        bk[j] = b; rec[j] = r;
        if (b >= 0) atomicAdd(&lh[b], 1);
    }
    __syncthreads();
    for (int i = t; i < NB; i += 256)
        gb[i] = lh[i] ? atomicAdd(&bcur[i], lh[i]) : 0;
    __syncthreads();
#pragma unroll
    for (int j = 0; j < 16; ++j) {
        int b = bk[j];
        if (b >= 0) {
            int slot = atomicAdd(&lc[b], 1);
            recs[gb[b] + slot] = rec[j];
        }
    }
}

__global__ __launch_bounds__(256) void k_bbuild(const unsigned int* __restrict__ recs,
                                                const int* __restrict__ bbase,
                                                int* __restrict__ ptr_all,
                                                int* __restrict__ col) {
    __shared__ int lh[512], lptr[512], lps[256];
    const int b = blockIdx.x, t = threadIdx.x;
    const int nd = (b < NB_M) ? min(512, N_MRNA - (b << 9))
                              : min(128, N_SRNA - ((b - NB_M) << 7));
    const int dst0 = (b < NB_M) ? (b << 9) : N_MRNA + ((b - NB_M) << 7);
    const int base = bbase[b];
    const int nbe = bbase[b + 1] - base;

    lh[t] = 0; lh[t + 256] = 0;
    __syncthreads();
    for (int e = t; e < nbe; e += 256)
        atomicAdd(&lh[recs[base + e] >> 17], 1);
    __syncthreads();

    int a0 = lh[2 * t], a1 = lh[2 * t + 1];
    int ps = a0 + a1;
    lps[t] = ps;
    __syncthreads();
    for (int off = 1; off < 256; off <<= 1) {
        int x = (t >= off) ? lps[t - off] : 0;
        __syncthreads();
        lps[t] += x;
        __syncthreads();
    }
    int ex = lps[t] - ps;
    lptr[2 * t] = ex;
    lptr[2 * t + 1] = ex + a0;
    __syncthreads();

    for (int d = t; d < nd; d += 256) ptr_all[dst0 + d] = base + lptr[d];

    lh[t] = lptr[t]; lh[t + 256] = lptr[t + 256];
    __syncthreads();
    for (int e = t; e < nbe; e += 256) {
        unsigned int r = recs[base + e];
        int slot = atomicAdd(&lh[r >> 17], 1);
        col[base + slot] = (int)(r & 0x1FFFFu);
    }
}

// ---------------------------------------------------------------------------
// Query CSR build (bucket queries by lbl_col). Records: .x = qidx,
// .y = (lcol<<15)|row  with lcol<2^9, row<2^15, qidx<2^19.
// ---------------------------------------------------------------------------

__global__ __launch_bounds__(256) void k_qhist(const int* __restrict__ lbl_col,
                                               int* __restrict__ qbcnt) {
    __shared__ int lh[NB_Q];
    for (int i = threadIdx.x; i < NB_Q; i += 256) lh[i] = 0;
    __syncthreads();
    int i0 = blockIdx.x * 4096;
#pragma unroll
    for (int j = 0; j < 16; ++j) {
        int i = i0 + j * 256 + threadIdx.x;
        if (i < NQ) atomicAdd(&lh[lbl_col[i] >> 9], 1);
    }
    __syncthreads();
    for (int i = threadIdx.x; i < NB_Q; i += 256)
        if (lh[i]) atomicAdd(&qbcnt[i], lh[i]);
}

__global__ __launch_bounds__(256) void k_qscan(const int* __restrict__ qbcnt,
                                               int* __restrict__ qbbase,
                                               int* __restrict__ qbcur,
                                               int* __restrict__ qptr_end) {
    __shared__ int s[256];
    int t = threadIdx.x;
    int v = (t < NB_Q) ? qbcnt[t] : 0;
    s[t] = v;
    __syncthreads();
    for (int off = 1; off < 256; off <<= 1) {
        int x = (t >= off) ? s[t - off] : 0;
        __syncthreads();
        s[t] += x;
        __syncthreads();
    }
    if (t < NB_Q) { int ex = s[t] - v; qbbase[t] = ex; qbcur[t] = ex; }
    if (t == 0) { qbbase[NB_Q] = NQ; *qptr_end = NQ; }
}

__global__ __launch_bounds__(256) void k_qscatter(const int* __restrict__ lbl_row,
                                                  const int* __restrict__ lbl_col,
                                                  int* __restrict__ qbcur,
                                                  uint2* __restrict__ qrecs) {
    __shared__ int lh[NB_Q], gb[NB_Q], lc[NB_Q];
    int t = threadIdx.x;
    for (int i = t; i < NB_Q; i += 256) { lh[i] = 0; lc[i] = 0; }
    __syncthreads();
    uint2 rec[16];
    int bk[16];
    int i0 = blockIdx.x * 4096;
#pragma unroll
    for (int j = 0; j < 16; ++j) {
        int i = i0 + j * 256 + t;
        int b = -1; uint2 r = make_uint2(0, 0);
        if (i < NQ) {
            int c = lbl_col[i];
            b = c >> 9;
            r.x = (unsigned int)i;
            r.y = ((unsigned int)(c - (b << 9)) << 15) | (unsigned int)lbl_row[i];
        }
        bk[j] = b; rec[j] = r;
        if (b >= 0) atomicAdd(&lh[b], 1);
    }
    __syncthreads();
    for (int i = t; i < NB_Q; i += 256)
        gb[i] = lh[i] ? atomicAdd(&qbcur[i], lh[i]) : 0;
    __syncthreads();
#pragma unroll
    for (int j = 0; j < 16; ++j) {
        int b = bk[j];
        if (b >= 0) {
            int slot = atomicAdd(&lc[b], 1);
            qrecs[gb[b] + slot] = rec[j];
        }
    }
}

// per-bucket finalize: qptr over cols (coalesced) + qdat = {row, qidx}
__global__ __launch_bounds__(256) void k_qbbuild(const uint2* __restrict__ qrecs,
                                                 const int* __restrict__ qbbase,
                                                 int* __restrict__ qptr,
                                                 uint2* __restrict__ qdat) {
    __shared__ int lh[512], lptr[512], lps[256];
    const int b = blockIdx.x, t = threadIdx.x;
    const int nd = min(512, N_MRNA - (b << 9));
    const int col0 = b << 9;
    const int base = qbbase[b];
    const int nbe = qbbase[b + 1] - base;

    lh[t] = 0; lh[t + 256] = 0;
    __syncthreads();
    for (int e = t; e < nbe; e += 256)
        atomicAdd(&lh[qrecs[base + e].y >> 15], 1);
    __syncthreads();

    int a0 = lh[2 * t], a1 = lh[2 * t + 1];
    int ps = a0 + a1;
    lps[t] = ps;
    __syncthreads();
    for (int off = 1; off < 256; off <<= 1) {
        int x = (t >= off) ? lps[t - off] : 0;
        __syncthreads();
        lps[t] += x;
        __syncthreads();
    }
    int ex = lps[t] - ps;
    lptr[2 * t] = ex;
    lptr[2 * t + 1] = ex + a0;
    __syncthreads();

    for (int d = t; d < nd; d += 256) qptr[col0 + d] = base + lptr[d];

    lh[t] = lptr[t]; lh[t + 256] = lptr[t + 256];
    __syncthreads();
    for (int e = t; e < nbe; e += 256) {
        uint2 r = qrecs[base + e];
        int slot = atomicAdd(&lh[r.y >> 15], 1);
        qdat[base + slot] = make_uint2(r.y & 0x7FFFu, r.x);   // {row, qidx}
    }
}

// ---------------------------------------------------------------------------
// fp32 -> bf16 conversion + Wt build (unchanged)
// ---------------------------------------------------------------------------
__global__ __launch_bounds__(256) void k_cvt_bf(const float* __restrict__ src,
                                                unsigned short* __restrict__ dst, int n4) {
    int i = blockIdx.x * 256 + threadIdx.x;
    int stride = gridDim.x * 256;
    for (; i < n4; i += stride) {
        float4 v = ((const float4*)src)[i];
        unsigned int p0 = (unsigned int)f2bf(v.x) | ((unsigned int)f2bf(v.y) << 16);
        unsigned int p1 = (unsigned int)f2bf(v.z) | ((unsigned int)f2bf(v.w) << 16);
        ((uint2*)dst)[i] = make_uint2(p0, p1);
    }
}

__global__ __launch_bounds__(256) void k_build_wt(const float* __restrict__ Wl,
                                                  const float* __restrict__ Wr,
                                                  unsigned short* __restrict__ Wt) {
    int tid = blockIdx.x * 256 + threadIdx.x;   // 32768 threads
    int c = tid & 127, k = tid >> 7;
    float v = (k < 128) ? Wl[k * 128 + c] : Wr[(k - 128) * 128 + c];
    Wt[c * 256 + k] = f2bf(v);
}

// ---------------------------------------------------------------------------
// Segment mean over bf16 rows (unchanged)
// ---------------------------------------------------------------------------
__global__ __launch_bounds__(256) void k_seg_mean_bf(const unsigned short* __restrict__ xsrc,
                                                     const int* __restrict__ rowptr,
                                                     const int* __restrict__ cols,
                                                     unsigned short* __restrict__ outm,
                                                     int ndst) {
    int wave = (blockIdx.x * 256 + threadIdx.x) >> 6;
    int lane = threadIdx.x & 63;
    if (wave >= ndst) return;
    int beg = rowptr[wave], end = rowptr[wave + 1];
    float a0x = 0.f, a0y = 0.f, a1x = 0.f, a1y = 0.f;
    float a2x = 0.f, a2y = 0.f, a3x = 0.f, a3y = 0.f;
    int e = beg;
    for (; e + 4 <= end; e += 4) {
        int s0 = cols[e], s1 = cols[e + 1], s2 = cols[e + 2], s3 = cols[e + 3];
        unsigned int v0 = ((const unsigned int*)(xsrc + (size_t)s0 * FDIM))[lane];
        unsigned int v1 = ((const unsigned int*)(xsrc + (size_t)s1 * FDIM))[lane];
        unsigned int v2 = ((const unsigned int*)(xsrc + (size_t)s2 * FDIM))[lane];
        unsigned int v3 = ((const unsigned int*)(xsrc + (size_t)s3 * FDIM))[lane];
        a0x += bf2f((unsigned short)v0); a0y += bf2f((unsigned short)(v0 >> 16));
        a1x += bf2f((unsigned short)v1); a1y += bf2f((unsigned short)(v1 >> 16));
        a2x += bf2f((unsigned short)v2); a2y += bf2f((unsigned short)(v2 >> 16));
        a3x += bf2f((unsigned short)v3); a3y += bf2f((unsigned short)(v3 >> 16));
    }
    for (; e < end; ++e) {
        unsigned int v = ((const unsigned int*)(xsrc + (size_t)cols[e] * FDIM))[lane];
        a0x += bf2f((unsigned short)v); a0y += bf2f((unsigned short)(v >> 16));
    }
    float inv = 1.0f / fmaxf((float)(end - beg), 1.0f);
    float ox = (a0x + a1x + a2x + a3x) * inv;
    float oy = (a0y + a1y + a2y + a3y) * inv;
    unsigned int packed = (unsigned int)f2bf(ox) | ((unsigned int)f2bf(oy) << 16);
    ((unsigned int*)(outm + (size_t)wave * FDIM))[lane] = packed;
}

// ---------------------------------------------------------------------------
// MFMA GEMM (unchanged)
// ---------------------------------------------------------------------------
template <bool RELU>
__global__ __launch_bounds__(256, 2) void k_gemm_mfma(const unsigned short* __restrict__ A0,
                                                      const unsigned short* __restrict__ A1,
                                                      const unsigned short* __restrict__ Wt,
                                                      const float* __restrict__ bias,
                                                      unsigned short* __restrict__ out,
                                                      int n) {
    __shared__ uint4 smem4[4352];
    char* smem = (char*)smem4;

    const int t = threadIdx.x;
#pragma unroll
    for (int i = 0; i < 16; ++i) {
        int j = i * 256 + t;
        int byteo = j << 4;
        int c = byteo >> 9;
        int off = byteo & 511;
        int swz = off ^ ((c & 7) << 4);
        uint4 v = ((const uint4*)Wt)[j];
        *(uint4*)(smem + c * 512 + swz) = v;
    }
    __syncthreads();

    const int w = t >> 6, l = t & 63;
    const int wr = w >> 1, wc = w & 1;
    const int rowbase = blockIdx.x * 128 + wr * 64;
    const int colbase = wc * 64;
    const int lr = l & 15;
    const int lk = (l >> 4) * 8;

    f32x4 acc[4][4];
#pragma unroll
    for (int a = 0; a < 4; ++a)
#pragma unroll
        for (int b = 0; b < 4; ++b)
#pragma unroll
            for (int e = 0; e < 4; ++e) acc[a][b][e] = 0.f;

    bf16x8 az;
#pragma unroll
    for (int e = 0; e < 8; ++e) az[e] = 0;

#pragma unroll
    for (int s = 0; s < 8; ++s) {
        const unsigned short* Abuf = (s < 4) ? A0 : A1;
        const int kk = (s & 3) * 32 + lk;
        bf16x8 afr[4];
#pragma unroll
        for (int af = 0; af < 4; ++af) {
            int row = rowbase + af * 16 + lr;
            afr[af] = (row < n) ? *(const bf16x8*)(Abuf + (size_t)row * FDIM + kk) : az;
        }
        bf16x8 bfr[4];
#pragma unroll
        for (int bf = 0; bf < 4; ++bf) {
            int c = colbase + bf * 16 + lr;
            int off = s * 64 + lk * 2;
            int swz = off ^ ((c & 7) << 4);
            bfr[bf] = *(const bf16x8*)(smem + c * 512 + swz);
        }
#pragma unroll
        for (int af = 0; af < 4; ++af)
#pragma unroll
            for (int bf = 0; bf < 4; ++bf)
                acc[af][bf] = __builtin_amdgcn_mfma_f32_16x16x32_bf16(afr[af], bfr[bf],
                                                                      acc[af][bf], 0, 0, 0);
    }

    __syncthreads();
    float* sD = (float*)(smem + w * 17408);

#pragma unroll
    for (int af = 0; af < 4; ++af)
#pragma unroll
        for (int bf = 0; bf < 4; ++bf)
#pragma unroll
            for (int r = 0; r < 4; ++r)
                sD[(af * 16 + (l >> 4) * 4 + r) * 68 + bf * 16 + lr] = acc[af][bf][r];

#pragma unroll
    for (int j = 0; j < 8; ++j) {
        int flat = j * 512 + l * 8;
        int row = flat >> 6;
        int c0 = flat & 63;
        int grow = rowbase + row;
        if (grow >= n) continue;
        float4 v0 = *(float4*)(&sD[row * 68 + c0]);
        float4 v1 = *(float4*)(&sD[row * 68 + c0 + 4]);
        int gc = colbase + c0;
        float4 b0 = *(const float4*)(bias + gc);
        float4 b1 = *(const float4*)(bias + gc + 4);
        float o[8] = {v0.x + b0.x, v0.y + b0.y, v0.z + b0.z, v0.w + b0.w,
                      v1.x + b1.x, v1.y + b1.y, v1.z + b1.z, v1.w + b1.w};
        if (RELU) {
#pragma unroll
            for (int e = 0; e < 8; ++e) o[e] = fmaxf(o[e], 0.f);
        }
        uint4 pv;
        pv.x = (unsigned int)f2bf(o[0]) | ((unsigned int)f2bf(o[1]) << 16);
        pv.y = (unsigned int)f2bf(o[2]) | ((unsigned int)f2bf(o[3]) << 16);
        pv.z = (unsigned int)f2bf(o[4]) | ((unsigned int)f2bf(o[5]) << 16);
        pv.w = (unsigned int)f2bf(o[6]) | ((unsigned int)f2bf(o[7]) << 16);
        *(uint4*)(out + (size_t)grow * FDIM + gc) = pv;
    }
}

// ---------------------------------------------------------------------------
// CSR decoder: one wave per mrna col; zM row register-resident across its
// queries; gathers zS rows only. out writes random 4B but out is 2MB (L2-held).
// ---------------------------------------------------------------------------
__global__ __launch_bounds__(256) void k_decoder_csr(const unsigned short* __restrict__ zS,
                                                     const unsigned short* __restrict__ zM,
                                                     const int* __restrict__ qptr,
                                                     const uint2* __restrict__ qdat,
                                                     float* __restrict__ out) {
    int c = (blockIdx.x * 256 + threadIdx.x) >> 6;
    int lane = threadIdx.x & 63;
    if (c >= N_MRNA) return;
    int beg = qptr[c], end = qptr[c + 1];
    if (beg == end) return;
    unsigned int vm = ((const unsigned int*)(zM + (size_t)c * FDIM))[lane];
    float mx = bf2f((unsigned short)vm), my = bf2f((unsigned short)(vm >> 16));
    int e = beg;
    for (; e + 2 <= end; e += 2) {
        uint2 d0 = qdat[e], d1 = qdat[e + 1];
        unsigned int va0 = ((const unsigned int*)(zS + (size_t)d0.x * FDIM))[lane];
        unsigned int va1 = ((const unsigned int*)(zS + (size_t)d1.x * FDIM))[lane];
        float s0 = bf2f((unsigned short)va0) * mx + bf2f((unsigned short)(va0 >> 16)) * my;
        float s1 = bf2f((unsigned short)va1) * mx + bf2f((unsigned short)(va1 >> 16)) * my;
        for (int off = 32; off; off >>= 1) {
            s0 += __shfl_down(s0, off);
            s1 += __shfl_down(s1, off);
        }
        if (lane == 0) { out[d0.y] = s0; out[d1.y] = s1; }
    }
    if (e < end) {
        uint2 d = qdat[e];
        unsigned int va = ((const unsigned int*)(zS + (size_t)d.x * FDIM))[lane];
        float s = bf2f((unsigned short)va) * mx + bf2f((unsigned short)(va >> 16)) * my;
        for (int off = 32; off; off >>= 1) s += __shfl_down(s, off);
        if (lane == 0) out[d.y] = s;
    }
}

// ---------------------------------------------------------------------------
// Launch
// ---------------------------------------------------------------------------
extern "C" void kernel_launch(void* const* d_in, const int* in_sizes, int n_in,
                              void* d_out, int out_size, void* d_ws, size_t ws_size,
                              hipStream_t stream) {
    const float* x_srna = (const float*)d_in[0];
    const float* x_mrna = (const float*)d_in[1];
    const int* src_sm = (const int*)d_in[2];
    const int* dst_sm = (const int*)d_in[3];
    const int* src_ms = (const int*)d_in[4];
    const int* dst_ms = (const int*)d_in[5];
    const int* lbl_row = (const int*)d_in[6];
    const int* lbl_col = (const int*)d_in[7];
    const float* W1l_sm = (const float*)d_in[8];
    const float* W1r_sm = (const float*)d_in[9];
    const float* W1l_ms = (const float*)d_in[10];
    const float* W1r_ms = (const float*)d_in[11];
    const float* W2l_sm = (const float*)d_in[12];
    const float* W2r_sm = (const float*)d_in[13];
    const float* W2l_ms = (const float*)d_in[14];
    const float* W2r_ms = (const float*)d_in[15];
    const float* b1_sm = (const float*)d_in[16];
    const float* b1_ms = (const float*)d_in[17];
    const float* b2_sm = (const float*)d_in[18];
    const float* b2_ms = (const float*)d_in[19];
    float* out = (float*)d_out;

    // Workspace layout (16B aligned)
    char* ws = (char*)d_ws;
    unsigned short* xS_bf   = (unsigned short*)(ws + 0);          //  5,120,000
    unsigned short* xM_bf   = (unsigned short*)(ws + 5120000);    // 25,600,000
    unsigned short* meanM   = (unsigned short*)(ws + 30720000);   // 25,600,000 (becomes zM)
    unsigned short* meanS   = (unsigned short*)(ws + 56320000);   //  5,120,000 (becomes zS)
    unsigned short* hM_bf   = (unsigned short*)(ws + 61440000);   // 25,600,000
    unsigned short* hS_bf   = (unsigned short*)(ws + 87040000);   //  5,120,000
    unsigned short* Wt1sm   = (unsigned short*)(ws + 92160000);   //     65,536
    unsigned short* Wt1ms   = (unsigned short*)(ws + 92225536);   //     65,536
    unsigned short* Wt2sm   = (unsigned short*)(ws + 92291072);   //     65,536
    unsigned short* Wt2ms   = (unsigned short*)(ws + 92356608);   //     65,536
    int* ptr_all            = (int*)(ws + 92422144);              //    480,016
    int* col_all            = (int*)(ws + 92902160);              //  8,000,000
    unsigned int* recs      = (unsigned int*)(ws + 100902160);    //  8,000,000
    int* bcnt               = (int*)(ws + 108902160);             //      1,424
    int* bbase              = (int*)(ws + 108903584);             //      1,424
    int* bcur               = (int*)(ws + 108905008);             //      1,424
    uint2* qrecs            = (uint2*)(ws + 108906432);           //  4,000,000
    uint2* qdat             = (uint2*)(ws + 112906432);           //  4,000,000
    int* qptr               = (int*)(ws + 116906432);             //    400,016 (100001 ints)
    int* qbcnt              = (int*)(ws + 117306448);             //        784
    int* qbbase             = (int*)(ws + 117307232);             //        788 (197 ints)
    int* qbcur              = (int*)(ws + 117308032);             //        784
    // total ~117.3 MB

    // --- dtype prep (independent of CSR) ---
    k_cvt_bf<<<2048, 256, 0, stream>>>(x_srna, xS_bf, N_SRNA * FDIM / 4);
    k_cvt_bf<<<2048, 256, 0, stream>>>(x_mrna, xM_bf, N_MRNA * FDIM / 4);
    k_build_wt<<<128, 256, 0, stream>>>(W1l_sm, W1r_sm, Wt1sm);
    k_build_wt<<<128, 256, 0, stream>>>(W1l_ms, W1r_ms, Wt1ms);
    k_build_wt<<<128, 256, 0, stream>>>(W2l_sm, W2r_sm, Wt2sm);
    k_build_wt<<<128, 256, 0, stream>>>(W2l_ms, W2r_ms, Wt2ms);

    // --- Bucketed CSR build (edges) ---
    hipMemsetAsync(bcnt, 0, NB * sizeof(int), stream);
    const int nblk = (2 * NE + 4095) / 4096;               // 489
    k_bhist<<<nblk, 256, 0, stream>>>(dst_sm, dst_ms, bcnt);
    k_bscan<<<1, 512, 0, stream>>>(bcnt, bbase, bcur, &ptr_all[NDST_ALL]);
    k_bscatter<<<nblk, 256, 0, stream>>>(src_sm, dst_sm, src_ms, dst_ms, bcur, recs);
    k_bbuild<<<NB, 256, 0, stream>>>(recs, bbase, ptr_all, col_all);

    // --- Query CSR build (decoder inversion) ---
    hipMemsetAsync(qbcnt, 0, NB_Q * sizeof(int), stream);
    const int nqblk = (NQ + 4095) / 4096;                  // 123
    k_qhist<<<nqblk, 256, 0, stream>>>(lbl_col, qbcnt);
    k_qscan<<<1, 256, 0, stream>>>(qbcnt, qbbase, qbcur, &qptr[N_MRNA]);
    k_qscatter<<<nqblk, 256, 0, stream>>>(lbl_row, lbl_col, qbcur, qrecs);
    k_qbbuild<<<NB_Q, 256, 0, stream>>>(qrecs, qbbase, qptr, qdat);

    // --- Layer 1 ---
    k_seg_mean_bf<<<(N_MRNA + 3) / 4, 256, 0, stream>>>(xS_bf, ptr_all, col_all, meanM, N_MRNA);
    k_seg_mean_bf<<<(N_SRNA + 3) / 4, 256, 0, stream>>>(xM_bf, ptr_all + N_MRNA, col_all, meanS, N_SRNA);
    k_gemm_mfma<true><<<(N_MRNA + 127) / 128, 256, 0, stream>>>(meanM, xM_bf, Wt1sm, b1_sm,
                                                                hM_bf, N_MRNA);
    k_gemm_mfma<true><<<(N_SRNA + 127) / 128, 256, 0, stream>>>(meanS, xS_bf, Wt1ms, b1_ms,
                                                                hS_bf, N_SRNA);

    // --- Layer 2 (z overwrites mean buffers in place) ---
    k_seg_mean_bf<<<(N_MRNA + 3) / 4, 256, 0, stream>>>(hS_bf, ptr_all, col_all, meanM, N_MRNA);
    k_seg_mean_bf<<<(N_SRNA + 3) / 4, 256, 0, stream>>>(hM_bf, ptr_all + N_MRNA, col_all, meanS, N_SRNA);
    k_gemm_mfma<false><<<(N_MRNA + 127) / 128, 256, 0, stream>>>(meanM, hM_bf, Wt2sm, b2_sm,
                                                                 meanM, N_MRNA);
    k_gemm_mfma<false><<<(N_SRNA + 127) / 128, 256, 0, stream>>>(meanS, hS_bf, Wt2ms, b2_ms,
                                                                 meanS, N_SRNA);

    // --- Decoder (CSR form) ---
    k_decoder_csr<<<(N_MRNA + 3) / 4, 256, 0, stream>>>(meanS, meanM, qptr, qdat, out);
}

// Round 6
// 523.474 us; speedup vs baseline: 1.0611x; 1.0611x over previous
//
#include <hip/hip_runtime.h>

// Problem constants (fixed by the reference)
#define N_SRNA  20000
#define N_MRNA  100000
#define FDIM    128
#define NE      1000000
#define NQ      500000
#define NDST_ALL (N_MRNA + N_SRNA)

// Buckets: mrna dsts in 512-wide buckets, srna dsts in 128-wide buckets.
// Fixed capacity per bucket (no hist/scan prepass): edge buckets mean
// 5120/6400 edges, sigma ~71/80 -> ECAP=8192 is >22 sigma. Query buckets
// mean 2560, sigma ~50 -> QCAP=4096 is ~30 sigma.
#define NB_M 196
#define NB_S 157
#define NB   (NB_M + NB_S)            // 353
#define NB_Q 196
#define ECAP 8192
#define QCAP 4096

typedef __attribute__((ext_vector_type(8))) short bf16x8;
typedef __attribute__((ext_vector_type(4))) float f32x4;

__device__ __forceinline__ unsigned short f2bf(float f) {
    unsigned int u = __float_as_uint(f);
    unsigned int r = (u + 0x7fffu + ((u >> 16) & 1u)) >> 16;   // RNE
    return (unsigned short)r;
}
__device__ __forceinline__ float bf2f(unsigned short h) {
    return __uint_as_float((unsigned int)h << 16);
}

// ---------------------------------------------------------------------------
// Edge binning: block reserves per-bucket runs off zeroed cursors, writes
// packed records (ldst<<17)|src into the bucket's fixed-capacity window.
// ---------------------------------------------------------------------------
__global__ __launch_bounds__(256) void k_bscatter(const int* __restrict__ src_sm,
                                                  const int* __restrict__ dst_sm,
                                                  const int* __restrict__ src_ms,
                                                  const int* __restrict__ dst_ms,
                                                  int* __restrict__ bcur,
                                                  unsigned int* __restrict__ recs) {
    __shared__ int lh[NB], gb[NB], lc[NB];
    int t = threadIdx.x;
    for (int i = t; i < NB; i += 256) { lh[i] = 0; lc[i] = 0; }
    __syncthreads();
    unsigned int rec[16];
    int bk[16];
    int i0 = blockIdx.x * 4096;
#pragma unroll
    for (int j = 0; j < 16; ++j) {
        int i = i0 + j * 256 + t;
        int b = -1; unsigned int r = 0;
        if (i < NE) {
            int d = dst_sm[i];
            b = d >> 9;
            r = ((unsigned int)(d - (b << 9)) << 17) | (unsigned int)src_sm[i];
        } else if (i < 2 * NE) {
            int jj = i - NE;
            int d = dst_ms[jj];
            int bs = d >> 7;
            b = NB_M + bs;
            r = ((unsigned int)(d - (bs << 7)) << 17) | (unsigned int)src_ms[jj];
        }
        bk[j] = b; rec[j] = r;
        if (b >= 0) atomicAdd(&lh[b], 1);
    }
    __syncthreads();
    for (int i = t; i < NB; i += 256)
        gb[i] = lh[i] ? atomicAdd(&bcur[i], lh[i]) : 0;
    __syncthreads();
#pragma unroll
    for (int j = 0; j < 16; ++j) {
        int b = bk[j];
        if (b >= 0) {
            int slot = atomicAdd(&lc[b], 1);
            recs[(size_t)b * ECAP + gb[b] + slot] = rec[j];
        }
    }
}

// Per-bucket CSR finalize: LDS dst histogram -> scan -> beg/deg (coalesced),
// then place src into the bucket's window of col.
__global__ __launch_bounds__(256) void k_bbuild(const unsigned int* __restrict__ recs,
                                                const int* __restrict__ bcur,
                                                int* __restrict__ begd,
                                                int* __restrict__ degd,
                                                int* __restrict__ col) {
    __shared__ int lh[512], lptr[512], lps[256];
    const int b = blockIdx.x, t = threadIdx.x;
    const int nd = (b < NB_M) ? min(512, N_MRNA - (b << 9))
                              : min(128, N_SRNA - ((b - NB_M) << 7));
    const int dst0 = (b < NB_M) ? (b << 9) : N_MRNA + ((b - NB_M) << 7);
    const int base = b * ECAP;
    const int nbe = bcur[b];

    lh[t] = 0; lh[t + 256] = 0;
    __syncthreads();
    for (int e = t; e < nbe; e += 256)
        atomicAdd(&lh[recs[(size_t)base + e] >> 17], 1);
    __syncthreads();

    int a0 = lh[2 * t], a1 = lh[2 * t + 1];
    int ps = a0 + a1;
    lps[t] = ps;
    __syncthreads();
    for (int off = 1; off < 256; off <<= 1) {
        int x = (t >= off) ? lps[t - off] : 0;
        __syncthreads();
        lps[t] += x;
        __syncthreads();
    }
    int ex = lps[t] - ps;
    lptr[2 * t] = ex;
    lptr[2 * t + 1] = ex + a0;
    __syncthreads();

    for (int d = t; d < nd; d += 256) {
        begd[dst0 + d] = base + lptr[d];
        degd[dst0 + d] = lh[d];
    }
    __syncthreads();
    lh[t] = lptr[t]; lh[t + 256] = lptr[t + 256];
    __syncthreads();
    for (int e = t; e < nbe; e += 256) {
        unsigned int r = recs[(size_t)base + e];
        int slot = atomicAdd(&lh[r >> 17], 1);
        col[base + slot] = (int)(r & 0x1FFFFu);
    }
}

// ---------------------------------------------------------------------------
// Query binning (by lbl_col). rec: .x = qidx, .y = (lcol<<15)|row.
// ---------------------------------------------------------------------------
__global__ __launch_bounds__(256) void k_qscatter(const int* __restrict__ lbl_row,
                                                  const int* __restrict__ lbl_col,
                                                  int* __restrict__ qbcur,
                                                  uint2* __restrict__ qrecs) {
    __shared__ int lh[NB_Q], gb[NB_Q], lc[NB_Q];
    int t = threadIdx.x;
    for (int i = t; i < NB_Q; i += 256) { lh[i] = 0; lc[i] = 0; }
    __syncthreads();
    uint2 rec[16];
    int bk[16];
    int i0 = blockIdx.x * 4096;
#pragma unroll
    for (int j = 0; j < 16; ++j) {
        int i = i0 + j * 256 + t;
        int b = -1; uint2 r = make_uint2(0, 0);
        if (i < NQ) {
            int c = lbl_col[i];
            b = c >> 9;
            r.x = (unsigned int)i;
            r.y = ((unsigned int)(c - (b << 9)) << 15) | (unsigned int)lbl_row[i];
        }
        bk[j] = b; rec[j] = r;
        if (b >= 0) atomicAdd(&lh[b], 1);
    }
    __syncthreads();
    for (int i = t; i < NB_Q; i += 256)
        gb[i] = lh[i] ? atomicAdd(&qbcur[i], lh[i]) : 0;
    __syncthreads();
#pragma unroll
    for (int j = 0; j < 16; ++j) {
        int b = bk[j];
        if (b >= 0) {
            int slot = atomicAdd(&lc[b], 1);
            qrecs[(size_t)b * QCAP + gb[b] + slot] = rec[j];
        }
    }
}

__global__ __launch_bounds__(256) void k_qbbuild(const uint2* __restrict__ qrecs,
                                                 const int* __restrict__ qbcur,
                                                 int* __restrict__ qbeg,
                                                 int* __restrict__ qdeg,
                                                 uint2* __restrict__ qdat) {
    __shared__ int lh[512], lptr[512], lps[256];
    const int b = blockIdx.x, t = threadIdx.x;
    const int nd = min(512, N_MRNA - (b << 9));
    const int col0 = b << 9;
    const int base = b * QCAP;
    const int nbe = qbcur[b];

    lh[t] = 0; lh[t + 256] = 0;
    __syncthreads();
    for (int e = t; e < nbe; e += 256)
        atomicAdd(&lh[qrecs[(size_t)base + e].y >> 15], 1);
    __syncthreads();

    int a0 = lh[2 * t], a1 = lh[2 * t + 1];
    int ps = a0 + a1;
    lps[t] = ps;
    __syncthreads();
    for (int off = 1; off < 256; off <<= 1) {
        int x = (t >= off) ? lps[t - off] : 0;
        __syncthreads();
        lps[t] += x;
        __syncthreads();
    }
    int ex = lps[t] - ps;
    lptr[2 * t] = ex;
    lptr[2 * t + 1] = ex + a0;
    __syncthreads();

    for (int d = t; d < nd; d += 256) {
        qbeg[col0 + d] = base + lptr[d];
        qdeg[col0 + d] = lh[d];
    }
    __syncthreads();
    lh[t] = lptr[t]; lh[t + 256] = lptr[t + 256];
    __syncthreads();
    for (int e = t; e < nbe; e += 256) {
        uint2 r = qrecs[(size_t)base + e];
        int slot = atomicAdd(&lh[r.y >> 15], 1);
        qdat[base + slot] = make_uint2(r.y & 0x7FFFu, r.x);   // {row, qidx}
    }
}

// ---------------------------------------------------------------------------
// fp32 -> bf16 conversion + Wt build
// ---------------------------------------------------------------------------
__global__ __launch_bounds__(256) void k_cvt_bf(const float* __restrict__ src,
                                                unsigned short* __restrict__ dst, int n4) {
    int i = blockIdx.x * 256 + threadIdx.x;
    int stride = gridDim.x * 256;
    for (; i < n4; i += stride) {
        float4 v = ((const float4*)src)[i];
        unsigned int p0 = (unsigned int)f2bf(v.x) | ((unsigned int)f2bf(v.y) << 16);
        unsigned int p1 = (unsigned int)f2bf(v.z) | ((unsigned int)f2bf(v.w) << 16);
        ((uint2*)dst)[i] = make_uint2(p0, p1);
    }
}

__global__ __launch_bounds__(256) void k_build_wt(const float* __restrict__ Wl,
                                                  const float* __restrict__ Wr,
                                                  unsigned short* __restrict__ Wt) {
    int tid = blockIdx.x * 256 + threadIdx.x;   // 32768 threads
    int c = tid & 127, k = tid >> 7;
    float v = (k < 128) ? Wl[k * 128 + c] : Wr[(k - 128) * 128 + c];
    Wt[c * 256 + k] = f2bf(v);
}

// ---------------------------------------------------------------------------
// Segment mean over bf16 rows: one wave per dst row (beg/deg form).
// ---------------------------------------------------------------------------
__global__ __launch_bounds__(256) void k_seg_mean_bf(const unsigned short* __restrict__ xsrc,
                                                     const int* __restrict__ begd,
                                                     const int* __restrict__ degd,
                                                     const int* __restrict__ cols,
                                                     unsigned short* __restrict__ outm,
                                                     int ndst) {
    int wave = (blockIdx.x * 256 + threadIdx.x) >> 6;
    int lane = threadIdx.x & 63;
    if (wave >= ndst) return;
    int beg = begd[wave], deg = degd[wave];
    int end = beg + deg;
    float a0x = 0.f, a0y = 0.f, a1x = 0.f, a1y = 0.f;
    float a2x = 0.f, a2y = 0.f, a3x = 0.f, a3y = 0.f;
    int e = beg;
    for (; e + 4 <= end; e += 4) {
        int s0 = cols[e], s1 = cols[e + 1], s2 = cols[e + 2], s3 = cols[e + 3];
        unsigned int v0 = ((const unsigned int*)(xsrc + (size_t)s0 * FDIM))[lane];
        unsigned int v1 = ((const unsigned int*)(xsrc + (size_t)s1 * FDIM))[lane];
        unsigned int v2 = ((const unsigned int*)(xsrc + (size_t)s2 * FDIM))[lane];
        unsigned int v3 = ((const unsigned int*)(xsrc + (size_t)s3 * FDIM))[lane];
        a0x += bf2f((unsigned short)v0); a0y += bf2f((unsigned short)(v0 >> 16));
        a1x += bf2f((unsigned short)v1); a1y += bf2f((unsigned short)(v1 >> 16));
        a2x += bf2f((unsigned short)v2); a2y += bf2f((unsigned short)(v2 >> 16));
        a3x += bf2f((unsigned short)v3); a3y += bf2f((unsigned short)(v3 >> 16));
    }
    for (; e < end; ++e) {
        unsigned int v = ((const unsigned int*)(xsrc + (size_t)cols[e] * FDIM))[lane];
        a0x += bf2f((unsigned short)v); a0y += bf2f((unsigned short)(v >> 16));
    }
    float inv = 1.0f / fmaxf((float)deg, 1.0f);
    float ox = (a0x + a1x + a2x + a3x) * inv;
    float oy = (a0y + a1y + a2y + a3y) * inv;
    unsigned int packed = (unsigned int)f2bf(ox) | ((unsigned int)f2bf(oy) << 16);
    ((unsigned int*)(outm + (size_t)wave * FDIM))[lane] = packed;
}

// ---------------------------------------------------------------------------
// MFMA GEMM (unchanged from round 4)
// ---------------------------------------------------------------------------
template <bool RELU>
__global__ __launch_bounds__(256, 2) void k_gemm_mfma(const unsigned short* __restrict__ A0,
                                                      const unsigned short* __restrict__ A1,
                                                      const unsigned short* __restrict__ Wt,
                                                      const float* __restrict__ bias,
                                                      unsigned short* __restrict__ out,
                                                      int n) {
    __shared__ uint4 smem4[4352];
    char* smem = (char*)smem4;

    const int t = threadIdx.x;
#pragma unroll
    for (int i = 0; i < 16; ++i) {
        int j = i * 256 + t;
        int byteo = j << 4;
        int c = byteo >> 9;
        int off = byteo & 511;
        int swz = off ^ ((c & 7) << 4);
        uint4 v = ((const uint4*)Wt)[j];
        *(uint4*)(smem + c * 512 + swz) = v;
    }
    __syncthreads();

    const int w = t >> 6, l = t & 63;
    const int wr = w >> 1, wc = w & 1;
    const int rowbase = blockIdx.x * 128 + wr * 64;
    const int colbase = wc * 64;
    const int lr = l & 15;
    const int lk = (l >> 4) * 8;

    f32x4 acc[4][4];
#pragma unroll
    for (int a = 0; a < 4; ++a)
#pragma unroll
        for (int b = 0; b < 4; ++b)
#pragma unroll
            for (int e = 0; e < 4; ++e) acc[a][b][e] = 0.f;

    bf16x8 az;
#pragma unroll
    for (int e = 0; e < 8; ++e) az[e] = 0;

#pragma unroll
    for (int s = 0; s < 8; ++s) {
        const unsigned short* Abuf = (s < 4) ? A0 : A1;
        const int kk = (s & 3) * 32 + lk;
        bf16x8 afr[4];
#pragma unroll
        for (int af = 0; af < 4; ++af) {
            int row = rowbase + af * 16 + lr;
            afr[af] = (row < n) ? *(const bf16x8*)(Abuf + (size_t)row * FDIM + kk) : az;
        }
        bf16x8 bfr[4];
#pragma unroll
        for (int bf = 0; bf < 4; ++bf) {
            int c = colbase + bf * 16 + lr;
            int off = s * 64 + lk * 2;
            int swz = off ^ ((c & 7) << 4);
            bfr[bf] = *(const bf16x8*)(smem + c * 512 + swz);
        }
#pragma unroll
        for (int af = 0; af < 4; ++af)
#pragma unroll
            for (int bf = 0; bf < 4; ++bf)
                acc[af][bf] = __builtin_amdgcn_mfma_f32_16x16x32_bf16(afr[af], bfr[bf],
                                                                      acc[af][bf], 0, 0, 0);
    }

    __syncthreads();
    float* sD = (float*)(smem + w * 17408);

#pragma unroll
    for (int af = 0; af < 4; ++af)
#pragma unroll
        for (int bf = 0; bf < 4; ++bf)
#pragma unroll
            for (int r = 0; r < 4; ++r)
                sD[(af * 16 + (l >> 4) * 4 + r) * 68 + bf * 16 + lr] = acc[af][bf][r];

#pragma unroll
    for (int j = 0; j < 8; ++j) {
        int flat = j * 512 + l * 8;
        int row = flat >> 6;
        int c0 = flat & 63;
        int grow = rowbase + row;
        if (grow >= n) continue;
        float4 v0 = *(float4*)(&sD[row * 68 + c0]);
        float4 v1 = *(float4*)(&sD[row * 68 + c0 + 4]);
        int gc = colbase + c0;
        float4 b0 = *(const float4*)(bias + gc);
        float4 b1 = *(const float4*)(bias + gc + 4);
        float o[8] = {v0.x + b0.x, v0.y + b0.y, v0.z + b0.z, v0.w + b0.w,
                      v1.x + b1.x, v1.y + b1.y, v1.z + b1.z, v1.w + b1.w};
        if (RELU) {
#pragma unroll
            for (int e = 0; e < 8; ++e) o[e] = fmaxf(o[e], 0.f);
        }
        uint4 pv;
        pv.x = (unsigned int)f2bf(o[0]) | ((unsigned int)f2bf(o[1]) << 16);
        pv.y = (unsigned int)f2bf(o[2]) | ((unsigned int)f2bf(o[3]) << 16);
        pv.z = (unsigned int)f2bf(o[4]) | ((unsigned int)f2bf(o[5]) << 16);
        pv.w = (unsigned int)f2bf(o[6]) | ((unsigned int)f2bf(o[7]) << 16);
        *(uint4*)(out + (size_t)grow * FDIM + gc) = pv;
    }
}

// ---------------------------------------------------------------------------
// CSR decoder: one wave per mrna col; zM row register-resident; 4-query
// unroll for memory-level parallelism (latency-bound kernel).
// ---------------------------------------------------------------------------
__global__ __launch_bounds__(256) void k_decoder_csr(const unsigned short* __restrict__ zS,
                                                     const unsigned short* __restrict__ zM,
                                                     const int* __restrict__ qbeg,
                                                     const int* __restrict__ qdeg,
                                                     const uint2* __restrict__ qdat,
                                                     float* __restrict__ out) {
    int c = (blockIdx.x * 256 + threadIdx.x) >> 6;
    int lane = threadIdx.x & 63;
    if (c >= N_MRNA) return;
    int cnt = qdeg[c];
    if (cnt == 0) return;
    int beg = qbeg[c];
    int end = beg + cnt;
    unsigned int vm = ((const unsigned int*)(zM + (size_t)c * FDIM))[lane];
    float mx = bf2f((unsigned short)vm), my = bf2f((unsigned short)(vm >> 16));
    int e = beg;
    for (; e + 4 <= end; e += 4) {
        uint2 d0 = qdat[e], d1 = qdat[e + 1], d2 = qdat[e + 2], d3 = qdat[e + 3];
        unsigned int va0 = ((const unsigned int*)(zS + (size_t)d0.x * FDIM))[lane];
        unsigned int va1 = ((const unsigned int*)(zS + (size_t)d1.x * FDIM))[lane];
        unsigned int va2 = ((const unsigned int*)(zS + (size_t)d2.x * FDIM))[lane];
        unsigned int va3 = ((const unsigned int*)(zS + (size_t)d3.x * FDIM))[lane];
        float s0 = bf2f((unsigned short)va0) * mx + bf2f((unsigned short)(va0 >> 16)) * my;
        float s1 = bf2f((unsigned short)va1) * mx + bf2f((unsigned short)(va1 >> 16)) * my;
        float s2 = bf2f((unsigned short)va2) * mx + bf2f((unsigned short)(va2 >> 16)) * my;
        float s3 = bf2f((unsigned short)va3) * mx + bf2f((unsigned short)(va3 >> 16)) * my;
        for (int off = 32; off; off >>= 1) {
            s0 += __shfl_down(s0, off);
            s1 += __shfl_down(s1, off);
            s2 += __shfl_down(s2, off);
            s3 += __shfl_down(s3, off);
        }
        if (lane == 0) { out[d0.y] = s0; out[d1.y] = s1; out[d2.y] = s2; out[d3.y] = s3; }
    }
    for (; e < end; ++e) {
        uint2 d = qdat[e];
        unsigned int va = ((const unsigned int*)(zS + (size_t)d.x * FDIM))[lane];
        float s = bf2f((unsigned short)va) * mx + bf2f((unsigned short)(va >> 16)) * my;
        for (int off = 32; off; off >>= 1) s += __shfl_down(s, off);
        if (lane == 0) out[d.y] = s;
    }
}

// ---------------------------------------------------------------------------
// Launch
// ---------------------------------------------------------------------------
extern "C" void kernel_launch(void* const* d_in, const int* in_sizes, int n_in,
                              void* d_out, int out_size, void* d_ws, size_t ws_size,
                              hipStream_t stream) {
    const float* x_srna = (const float*)d_in[0];
    const float* x_mrna = (const float*)d_in[1];
    const int* src_sm = (const int*)d_in[2];
    const int* dst_sm = (const int*)d_in[3];
    const int* src_ms = (const int*)d_in[4];
    const int* dst_ms = (const int*)d_in[5];
    const int* lbl_row = (const int*)d_in[6];
    const int* lbl_col = (const int*)d_in[7];
    const float* W1l_sm = (const float*)d_in[8];
    const float* W1r_sm = (const float*)d_in[9];
    const float* W1l_ms = (const float*)d_in[10];
    const float* W1r_ms = (const float*)d_in[11];
    const float* W2l_sm = (const float*)d_in[12];
    const float* W2r_sm = (const float*)d_in[13];
    const float* W2l_ms = (const float*)d_in[14];
    const float* W2r_ms = (const float*)d_in[15];
    const float* b1_sm = (const float*)d_in[16];
    const float* b1_ms = (const float*)d_in[17];
    const float* b2_sm = (const float*)d_in[18];
    const float* b2_ms = (const float*)d_in[19];
    float* out = (float*)d_out;

    // Workspace layout (16B aligned)
    char* ws = (char*)d_ws;
    unsigned short* xS_bf   = (unsigned short*)(ws + 0);           //   5,120,000
    unsigned short* xM_bf   = (unsigned short*)(ws + 5120000);     //  25,600,000
    unsigned short* meanM   = (unsigned short*)(ws + 30720000);    //  25,600,000 (becomes zM)
    unsigned short* meanS   = (unsigned short*)(ws + 56320000);    //   5,120,000 (becomes zS)
    unsigned short* hM_bf   = (unsigned short*)(ws + 61440000);    //  25,600,000
    unsigned short* hS_bf   = (unsigned short*)(ws + 87040000);    //   5,120,000
    unsigned short* Wt1sm   = (unsigned short*)(ws + 92160000);    //      65,536
    unsigned short* Wt1ms   = (unsigned short*)(ws + 92225536);    //      65,536
    unsigned short* Wt2sm   = (unsigned short*)(ws + 92291072);    //      65,536
    unsigned short* Wt2ms   = (unsigned short*)(ws + 92356608);    //      65,536
    int* begd               = (int*)(ws + 92422144);               //     480,000
    int* degd               = (int*)(ws + 92902144);               //     480,000
    int* col_all            = (int*)(ws + 93382144);               //  11,567,104 (353*8192*4)
    unsigned int* recs      = (unsigned int*)(ws + 104949248);     //  11,567,104
    uint2* qrecs            = (uint2*)(ws + 116516352);            //   6,422,528 (196*4096*8)
    uint2* qdat             = (uint2*)(ws + 122938880);            //   6,422,528
    int* qbeg               = (int*)(ws + 129361408);              //     400,000
    int* qdeg               = (int*)(ws + 129761408);              //     400,000
    int* bcur               = (int*)(ws + 130161408);              //       1,412 (353 ints)
    int* qbcur              = (int*)(ws + 130162820);              //         784 (196 ints)
    // total ~130.2 MB (< the 132.3 MB used successfully in round 0)

    // --- dtype prep ---
    k_cvt_bf<<<2048, 256, 0, stream>>>(x_srna, xS_bf, N_SRNA * FDIM / 4);
    k_cvt_bf<<<2048, 256, 0, stream>>>(x_mrna, xM_bf, N_MRNA * FDIM / 4);
    k_build_wt<<<128, 256, 0, stream>>>(W1l_sm, W1r_sm, Wt1sm);
    k_build_wt<<<128, 256, 0, stream>>>(W1l_ms, W1r_ms, Wt1ms);
    k_build_wt<<<128, 256, 0, stream>>>(W2l_sm, W2r_sm, Wt2sm);
    k_build_wt<<<128, 256, 0, stream>>>(W2l_ms, W2r_ms, Wt2ms);

    // --- zero both cursor arrays with ONE memset (they are adjacent) ---
    hipMemsetAsync(bcur, 0, (NB + NB_Q) * sizeof(int), stream);

    // --- Edge CSR (fixed-capacity buckets; no hist/scan prepass) ---
    const int nblk = (2 * NE + 4095) / 4096;               // 489
    k_bscatter<<<nblk, 256, 0, stream>>>(src_sm, dst_sm, src_ms, dst_ms, bcur, recs);
    k_bbuild<<<NB, 256, 0, stream>>>(recs, bcur, begd, degd, col_all);

    // --- Query CSR (fixed-capacity buckets) ---
    const int nqblk = (NQ + 4095) / 4096;                  // 123
    k_qscatter<<<nqblk, 256, 0, stream>>>(lbl_row, lbl_col, qbcur, qrecs);
    k_qbbuild<<<NB_Q, 256, 0, stream>>>(qrecs, qbcur, qbeg, qdeg, qdat);

    // --- Layer 1 ---
    k_seg_mean_bf<<<(N_MRNA + 3) / 4, 256, 0, stream>>>(xS_bf, begd, degd, col_all,
                                                        meanM, N_MRNA);
    k_seg_mean_bf<<<(N_SRNA + 3) / 4, 256, 0, stream>>>(xM_bf, begd + N_MRNA, degd + N_MRNA,
                                                        col_all, meanS, N_SRNA);
    k_gemm_mfma<true><<<(N_MRNA + 127) / 128, 256, 0, stream>>>(meanM, xM_bf, Wt1sm, b1_sm,
                                                                hM_bf, N_MRNA);
    k_gemm_mfma<true><<<(N_SRNA + 127) / 128, 256, 0, stream>>>(meanS, xS_bf, Wt1ms, b1_ms,
                                                                hS_bf, N_SRNA);

    // --- Layer 2 (z overwrites mean buffers in place) ---
    k_seg_mean_bf<<<(N_MRNA + 3) / 4, 256, 0, stream>>>(hS_bf, begd, degd, col_all,
                                                        meanM, N_MRNA);
    k_seg_mean_bf<<<(N_SRNA + 3) / 4, 256, 0, stream>>>(hM_bf, begd + N_MRNA, degd + N_MRNA,
                                                        col_all, meanS, N_SRNA);
    k_gemm_mfma<false><<<(N_MRNA + 127) / 128, 256, 0, stream>>>(meanM, hM_bf, Wt2sm, b2_sm,
                                                                 meanM, N_MRNA);
    k_gemm_mfma<false><<<(N_SRNA + 127) / 128, 256, 0, stream>>>(meanS, hS_bf, Wt2ms, b2_ms,
                                                                 meanS, N_SRNA);

    // --- Decoder ---
    k_decoder_csr<<<(N_MRNA + 3) / 4, 256, 0, stream>>>(meanS, meanM, qbeg, qdeg, qdat, out);
}

// Round 8
// 449.357 us; speedup vs baseline: 1.2361x; 1.1649x over previous
//
#include <hip/hip_runtime.h>

// Problem constants (fixed by the reference)
#define N_SRNA  20000
#define N_MRNA  100000
#define FDIM    128
#define NE      1000000
#define NQ      500000
#define NDST_ALL (N_MRNA + N_SRNA)

// Fixed-capacity buckets (no hist/scan prepass); see round-5 sigma analysis.
#define NB_M 196
#define NB_S 157
#define NB   (NB_M + NB_S)            // 353
#define NB_Q 196
#define ECAP 8192
#define QCAP 4096

typedef __attribute__((ext_vector_type(8))) short bf16x8;
typedef __attribute__((ext_vector_type(4))) float f32x4;

__device__ __forceinline__ unsigned short f2bf(float f) {
    unsigned int u = __float_as_uint(f);
    unsigned int r = (u + 0x7fffu + ((u >> 16) & 1u)) >> 16;   // RNE
    return (unsigned short)r;
}
__device__ __forceinline__ float bf2f(unsigned short h) {
    return __uint_as_float((unsigned int)h << 16);
}

// ---------------------------------------------------------------------------
// Edge binning (unchanged from round 5)
// ---------------------------------------------------------------------------
__global__ __launch_bounds__(256) void k_bscatter(const int* __restrict__ src_sm,
                                                  const int* __restrict__ dst_sm,
                                                  const int* __restrict__ src_ms,
                                                  const int* __restrict__ dst_ms,
                                                  int* __restrict__ bcur,
                                                  unsigned int* __restrict__ recs) {
    __shared__ int lh[NB], gb[NB], lc[NB];
    int t = threadIdx.x;
    for (int i = t; i < NB; i += 256) { lh[i] = 0; lc[i] = 0; }
    __syncthreads();
    unsigned int rec[16];
    int bk[16];
    int i0 = blockIdx.x * 4096;
#pragma unroll
    for (int j = 0; j < 16; ++j) {
        int i = i0 + j * 256 + t;
        int b = -1; unsigned int r = 0;
        if (i < NE) {
            int d = dst_sm[i];
            b = d >> 9;
            r = ((unsigned int)(d - (b << 9)) << 17) | (unsigned int)src_sm[i];
        } else if (i < 2 * NE) {
            int jj = i - NE;
            int d = dst_ms[jj];
            int bs = d >> 7;
            b = NB_M + bs;
            r = ((unsigned int)(d - (bs << 7)) << 17) | (unsigned int)src_ms[jj];
        }
        bk[j] = b; rec[j] = r;
        if (b >= 0) atomicAdd(&lh[b], 1);
    }
    __syncthreads();
    for (int i = t; i < NB; i += 256)
        gb[i] = lh[i] ? atomicAdd(&bcur[i], lh[i]) : 0;
    __syncthreads();
#pragma unroll
    for (int j = 0; j < 16; ++j) {
        int b = bk[j];
        if (b >= 0) {
            int slot = atomicAdd(&lc[b], 1);
            recs[(size_t)b * ECAP + gb[b] + slot] = rec[j];
        }
    }
}

__global__ __launch_bounds__(256) void k_bbuild(const unsigned int* __restrict__ recs,
                                                const int* __restrict__ bcur,
                                                int* __restrict__ begd,
                                                int* __restrict__ degd,
                                                int* __restrict__ col) {
    __shared__ int lh[512], lptr[512], lps[256];
    const int b = blockIdx.x, t = threadIdx.x;
    const int nd = (b < NB_M) ? min(512, N_MRNA - (b << 9))
                              : min(128, N_SRNA - ((b - NB_M) << 7));
    const int dst0 = (b < NB_M) ? (b << 9) : N_MRNA + ((b - NB_M) << 7);
    const int base = b * ECAP;
    const int nbe = bcur[b];

    lh[t] = 0; lh[t + 256] = 0;
    __syncthreads();
    for (int e = t; e < nbe; e += 256)
        atomicAdd(&lh[recs[(size_t)base + e] >> 17], 1);
    __syncthreads();

    int a0 = lh[2 * t], a1 = lh[2 * t + 1];
    int ps = a0 + a1;
    lps[t] = ps;
    __syncthreads();
    for (int off = 1; off < 256; off <<= 1) {
        int x = (t >= off) ? lps[t - off] : 0;
        __syncthreads();
        lps[t] += x;
        __syncthreads();
    }
    int ex = lps[t] - ps;
    lptr[2 * t] = ex;
    lptr[2 * t + 1] = ex + a0;
    __syncthreads();

    for (int d = t; d < nd; d += 256) {
        begd[dst0 + d] = base + lptr[d];
        degd[dst0 + d] = lh[d];
    }
    __syncthreads();
    lh[t] = lptr[t]; lh[t + 256] = lptr[t + 256];
    __syncthreads();
    for (int e = t; e < nbe; e += 256) {
        unsigned int r = recs[(size_t)base + e];
        int slot = atomicAdd(&lh[r >> 17], 1);
        col[base + slot] = (int)(r & 0x1FFFFu);
    }
}

// ---------------------------------------------------------------------------
// Query binning (unchanged from round 5)
// ---------------------------------------------------------------------------
__global__ __launch_bounds__(256) void k_qscatter(const int* __restrict__ lbl_row,
                                                  const int* __restrict__ lbl_col,
                                                  int* __restrict__ qbcur,
                                                  uint2* __restrict__ qrecs) {
    __shared__ int lh[NB_Q], gb[NB_Q], lc[NB_Q];
    int t = threadIdx.x;
    for (int i = t; i < NB_Q; i += 256) { lh[i] = 0; lc[i] = 0; }
    __syncthreads();
    uint2 rec[16];
    int bk[16];
    int i0 = blockIdx.x * 4096;
#pragma unroll
    for (int j = 0; j < 16; ++j) {
        int i = i0 + j * 256 + t;
        int b = -1; uint2 r = make_uint2(0, 0);
        if (i < NQ) {
            int c = lbl_col[i];
            b = c >> 9;
            r.x = (unsigned int)i;
            r.y = ((unsigned int)(c - (b << 9)) << 15) | (unsigned int)lbl_row[i];
        }
        bk[j] = b; rec[j] = r;
        if (b >= 0) atomicAdd(&lh[b], 1);
    }
    __syncthreads();
    for (int i = t; i < NB_Q; i += 256)
        gb[i] = lh[i] ? atomicAdd(&qbcur[i], lh[i]) : 0;
    __syncthreads();
#pragma unroll
    for (int j = 0; j < 16; ++j) {
        int b = bk[j];
        if (b >= 0) {
            int slot = atomicAdd(&lc[b], 1);
            qrecs[(size_t)b * QCAP + gb[b] + slot] = rec[j];
        }
    }
}

__global__ __launch_bounds__(256) void k_qbbuild(const uint2* __restrict__ qrecs,
                                                 const int* __restrict__ qbcur,
                                                 int* __restrict__ qbeg,
                                                 int* __restrict__ qdeg,
                                                 uint2* __restrict__ qdat) {
    __shared__ int lh[512], lptr[512], lps[256];
    const int b = blockIdx.x, t = threadIdx.x;
    const int nd = min(512, N_MRNA - (b << 9));
    const int col0 = b << 9;
    const int base = b * QCAP;
    const int nbe = qbcur[b];

    lh[t] = 0; lh[t + 256] = 0;
    __syncthreads();
    for (int e = t; e < nbe; e += 256)
        atomicAdd(&lh[qrecs[(size_t)base + e].y >> 15], 1);
    __syncthreads();

    int a0 = lh[2 * t], a1 = lh[2 * t + 1];
    int ps = a0 + a1;
    lps[t] = ps;
    __syncthreads();
    for (int off = 1; off < 256; off <<= 1) {
        int x = (t >= off) ? lps[t - off] : 0;
        __syncthreads();
        lps[t] += x;
        __syncthreads();
    }
    int ex = lps[t] - ps;
    lptr[2 * t] = ex;
    lptr[2 * t + 1] = ex + a0;
    __syncthreads();

    for (int d = t; d < nd; d += 256) {
        qbeg[col0 + d] = base + lptr[d];
        qdeg[col0 + d] = lh[d];
    }
    __syncthreads();
    lh[t] = lptr[t]; lh[t + 256] = lptr[t + 256];
    __syncthreads();
    for (int e = t; e < nbe; e += 256) {
        uint2 r = qrecs[(size_t)base + e];
        int slot = atomicAdd(&lh[r.y >> 15], 1);
        qdat[base + slot] = make_uint2(r.y & 0x7FFFu, r.x);   // {row, qidx}
    }
}

// ---------------------------------------------------------------------------
// fp32 -> bf16 conversion; fused 4x Wt build
// ---------------------------------------------------------------------------
__global__ __launch_bounds__(256) void k_cvt_bf(const float* __restrict__ src,
                                                unsigned short* __restrict__ dst, int n4) {
    int i = blockIdx.x * 256 + threadIdx.x;
    int stride = gridDim.x * 256;
    for (; i < n4; i += stride) {
        float4 v = ((const float4*)src)[i];
        unsigned int p0 = (unsigned int)f2bf(v.x) | ((unsigned int)f2bf(v.y) << 16);
        unsigned int p1 = (unsigned int)f2bf(v.z) | ((unsigned int)f2bf(v.w) << 16);
        ((uint2*)dst)[i] = make_uint2(p0, p1);
    }
}

// Wt[c][k] = bf16(k<128 ? Wl[k][c] : Wr[k-128][c]); 4 weight sets, 128 blocks each.
__global__ __launch_bounds__(256) void k_build_wt4(
        const float* __restrict__ Wl0, const float* __restrict__ Wr0, unsigned short* __restrict__ Wt0,
        const float* __restrict__ Wl1, const float* __restrict__ Wr1, unsigned short* __restrict__ Wt1,
        const float* __restrict__ Wl2, const float* __restrict__ Wr2, unsigned short* __restrict__ Wt2,
        const float* __restrict__ Wl3, const float* __restrict__ Wr3, unsigned short* __restrict__ Wt3) {
    int g = blockIdx.x >> 7;
    const float* Wl; const float* Wr; unsigned short* Wt;
    if (g == 0)      { Wl = Wl0; Wr = Wr0; Wt = Wt0; }
    else if (g == 1) { Wl = Wl1; Wr = Wr1; Wt = Wt1; }
    else if (g == 2) { Wl = Wl2; Wr = Wr2; Wt = Wt2; }
    else             { Wl = Wl3; Wr = Wr3; Wt = Wt3; }
    int tid = (blockIdx.x & 127) * 256 + threadIdx.x;   // 0..32767
    int c = tid & 127, k = tid >> 7;
    float v = (k < 128) ? Wl[k * 128 + c] : Wr[(k - 128) * 128 + c];
    Wt[c * 256 + k] = f2bf(v);
}

// ---------------------------------------------------------------------------
// Fused segment mean (both node types): wave per dst row. Quarter-wave
// layout: lane l -> quarter q=l>>4 handles edge e+q, 16 lanes x 16B per row.
// 4 gathers in flight per iteration; cross-quarter reduce via shfl_xor 16/32.
// ---------------------------------------------------------------------------
__global__ __launch_bounds__(256) void k_seg_mean2(const unsigned short* __restrict__ srcA,
                                                   const unsigned short* __restrict__ srcB,
                                                   const int* __restrict__ begd,
                                                   const int* __restrict__ degd,
                                                   const int* __restrict__ cols,
                                                   unsigned short* __restrict__ outA,
                                                   unsigned short* __restrict__ outB,
                                                   int nA, int nTot) {
    int wave = (blockIdx.x * 256 + threadIdx.x) >> 6;
    int l = threadIdx.x & 63;
    if (wave >= nTot) return;
    const int q = l >> 4, lq = l & 15;
    const unsigned short* xs;
    unsigned short* o;
    if (wave < nA) { xs = srcA; o = outA + (size_t)wave * FDIM; }
    else           { xs = srcB; o = outB + (size_t)(wave - nA) * FDIM; }

    int beg = begd[wave], deg = degd[wave];
    float acc[8];
#pragma unroll
    for (int k = 0; k < 8; ++k) acc[k] = 0.f;

    int e = 0;
    for (; e + 8 <= deg; e += 8) {
        int s0 = cols[beg + e + q];
        int s1 = cols[beg + e + 4 + q];
        bf16x8 v0 = *(const bf16x8*)(xs + (size_t)s0 * FDIM + lq * 8);
        bf16x8 v1 = *(const bf16x8*)(xs + (size_t)s1 * FDIM + lq * 8);
#pragma unroll
        for (int k = 0; k < 8; ++k) acc[k] += bf2f((unsigned short)v0[k]);
#pragma unroll
        for (int k = 0; k < 8; ++k) acc[k] += bf2f((unsigned short)v1[k]);
    }
    for (; e < deg; e += 4) {
        bool valid = (e + q) < deg;
        int idx = beg + min(e + q, max(deg - 1, 0));
        int s = cols[idx];
        bf16x8 v = *(const bf16x8*)(xs + (size_t)s * FDIM + lq * 8);
        if (valid) {
#pragma unroll
            for (int k = 0; k < 8; ++k) acc[k] += bf2f((unsigned short)v[k]);
        }
    }
    // cross-quarter reduce: all lanes end with total for feature slice lq*8..
#pragma unroll
    for (int k = 0; k < 8; ++k) {
        acc[k] += __shfl_xor(acc[k], 16);
        acc[k] += __shfl_xor(acc[k], 32);
    }
    if (q == 0) {
        float inv = 1.0f / fmaxf((float)deg, 1.0f);
        uint4 pv;
        pv.x = (unsigned int)f2bf(acc[0] * inv) | ((unsigned int)f2bf(acc[1] * inv) << 16);
        pv.y = (unsigned int)f2bf(acc[2] * inv) | ((unsigned int)f2bf(acc[3] * inv) << 16);
        pv.z = (unsigned int)f2bf(acc[4] * inv) | ((unsigned int)f2bf(acc[5] * inv) << 16);
        pv.w = (unsigned int)f2bf(acc[6] * inv) | ((unsigned int)f2bf(acc[7] * inv) << 16);
        ((uint4*)o)[lq] = pv;
    }
}

// ---------------------------------------------------------------------------
// MFMA GEMM, both node types fused in one dispatch (pointer select by block).
// ---------------------------------------------------------------------------
template <bool RELU>
__global__ __launch_bounds__(256, 2) void k_gemm_mfma2(
        const unsigned short* __restrict__ A0a, const unsigned short* __restrict__ A1a,
        const unsigned short* __restrict__ Wta, const float* __restrict__ biasa,
        unsigned short* __restrict__ outa, int na, int nblka,
        const unsigned short* __restrict__ A0b, const unsigned short* __restrict__ A1b,
        const unsigned short* __restrict__ Wtb, const float* __restrict__ biasb,
        unsigned short* __restrict__ outb, int nb) {
    __shared__ uint4 smem4[4352];
    char* smem = (char*)smem4;

    const unsigned short *A0, *A1, *Wt;
    const float* bias;
    unsigned short* out;
    int n, bid;
    if ((int)blockIdx.x < nblka) {
        A0 = A0a; A1 = A1a; Wt = Wta; bias = biasa; out = outa; n = na; bid = blockIdx.x;
    } else {
        A0 = A0b; A1 = A1b; Wt = Wtb; bias = biasb; out = outb; n = nb; bid = blockIdx.x - nblka;
    }

    const int t = threadIdx.x;
#pragma unroll
    for (int i = 0; i < 16; ++i) {
        int j = i * 256 + t;
        int byteo = j << 4;
        int c = byteo >> 9;
        int off = byteo & 511;
        int swz = off ^ ((c & 7) << 4);
        uint4 v = ((const uint4*)Wt)[j];
        *(uint4*)(smem + c * 512 + swz) = v;
    }
    __syncthreads();

    const int w = t >> 6, l = t & 63;
    const int wr = w >> 1, wc = w & 1;
    const int rowbase = bid * 128 + wr * 64;
    const int colbase = wc * 64;
    const int lr = l & 15;
    const int lk = (l >> 4) * 8;

    f32x4 acc[4][4];
#pragma unroll
    for (int a = 0; a < 4; ++a)
#pragma unroll
        for (int b = 0; b < 4; ++b)
#pragma unroll
            for (int e = 0; e < 4; ++e) acc[a][b][e] = 0.f;

    bf16x8 az;
#pragma unroll
    for (int e = 0; e < 8; ++e) az[e] = 0;

#pragma unroll
    for (int s = 0; s < 8; ++s) {
        const unsigned short* Abuf = (s < 4) ? A0 : A1;
        const int kk = (s & 3) * 32 + lk;
        bf16x8 afr[4];
#pragma unroll
        for (int af = 0; af < 4; ++af) {
            int row = rowbase + af * 16 + lr;
            afr[af] = (row < n) ? *(const bf16x8*)(Abuf + (size_t)row * FDIM + kk) : az;
        }
        bf16x8 bfr[4];
#pragma unroll
        for (int bf = 0; bf < 4; ++bf) {
            int c = colbase + bf * 16 + lr;
            int off = s * 64 + lk * 2;
            int swz = off ^ ((c & 7) << 4);
            bfr[bf] = *(const bf16x8*)(smem + c * 512 + swz);
        }
#pragma unroll
        for (int af = 0; af < 4; ++af)
#pragma unroll
            for (int bf = 0; bf < 4; ++bf)
                acc[af][bf] = __builtin_amdgcn_mfma_f32_16x16x32_bf16(afr[af], bfr[bf],
                                                                      acc[af][bf], 0, 0, 0);
    }

    __syncthreads();
    float* sD = (float*)(smem + w * 17408);

#pragma unroll
    for (int af = 0; af < 4; ++af)
#pragma unroll
        for (int bf = 0; bf < 4; ++bf)
#pragma unroll
            for (int r = 0; r < 4; ++r)
                sD[(af * 16 + (l >> 4) * 4 + r) * 68 + bf * 16 + lr] = acc[af][bf][r];

#pragma unroll
    for (int j = 0; j < 8; ++j) {
        int flat = j * 512 + l * 8;
        int row = flat >> 6;
        int c0 = flat & 63;
        int grow = rowbase + row;
        if (grow >= n) continue;
        float4 v0 = *(float4*)(&sD[row * 68 + c0]);
        float4 v1 = *(float4*)(&sD[row * 68 + c0 + 4]);
        int gc = colbase + c0;
        float4 b0 = *(const float4*)(bias + gc);
        float4 b1 = *(const float4*)(bias + gc + 4);
        float o[8] = {v0.x + b0.x, v0.y + b0.y, v0.z + b0.z, v0.w + b0.w,
                      v1.x + b1.x, v1.y + b1.y, v1.z + b1.z, v1.w + b1.w};
        if (RELU) {
#pragma unroll
            for (int e = 0; e < 8; ++e) o[e] = fmaxf(o[e], 0.f);
        }
        uint4 pv;
        pv.x = (unsigned int)f2bf(o[0]) | ((unsigned int)f2bf(o[1]) << 16);
        pv.y = (unsigned int)f2bf(o[2]) | ((unsigned int)f2bf(o[3]) << 16);
        pv.z = (unsigned int)f2bf(o[4]) | ((unsigned int)f2bf(o[5]) << 16);
        pv.w = (unsigned int)f2bf(o[6]) | ((unsigned int)f2bf(o[7]) << 16);
        *(uint4*)(out + (size_t)grow * FDIM + gc) = pv;
    }
}

// ---------------------------------------------------------------------------
// CSR decoder, quarter-wave: wave per mrna col; quarter q handles query e+q;
// 16 lanes x 16B per zS row; reduce via shfl_xor 1/2/4/8 (in-quarter).
// ---------------------------------------------------------------------------
__global__ __launch_bounds__(256) void k_decoder_csr(const unsigned short* __restrict__ zS,
                                                     const unsigned short* __restrict__ zM,
                                                     const int* __restrict__ qbeg,
                                                     const int* __restrict__ qdeg,
                                                     const uint2* __restrict__ qdat,
                                                     float* __restrict__ out) {
    int c = (blockIdx.x * 256 + threadIdx.x) >> 6;
    int l = threadIdx.x & 63;
    if (c >= N_MRNA) return;
    int cnt = qdeg[c];
    if (cnt == 0) return;
    int beg = qbeg[c];
    const int q = l >> 4, lq = l & 15;

    bf16x8 vm = *(const bf16x8*)(zM + (size_t)c * FDIM + lq * 8);
    float mxf[8];
#pragma unroll
    for (int k = 0; k < 8; ++k) mxf[k] = bf2f((unsigned short)vm[k]);

    for (int e = 0; e < cnt; e += 4) {
        bool valid = (e + q) < cnt;
        int idx = beg + min(e + q, cnt - 1);
        uint2 d = qdat[idx];
        bf16x8 va = *(const bf16x8*)(zS + (size_t)d.x * FDIM + lq * 8);
        float s = 0.f;
#pragma unroll
        for (int k = 0; k < 8; ++k) s += bf2f((unsigned short)va[k]) * mxf[k];
        s += __shfl_xor(s, 1);
        s += __shfl_xor(s, 2);
        s += __shfl_xor(s, 4);
        s += __shfl_xor(s, 8);
        if (valid && lq == 0) out[d.y] = s;
    }
}

// ---------------------------------------------------------------------------
// Launch
// ---------------------------------------------------------------------------
extern "C" void kernel_launch(void* const* d_in, const int* in_sizes, int n_in,
                              void* d_out, int out_size, void* d_ws, size_t ws_size,
                              hipStream_t stream) {
    const float* x_srna = (const float*)d_in[0];
    const float* x_mrna = (const float*)d_in[1];
    const int* src_sm = (const int*)d_in[2];
    const int* dst_sm = (const int*)d_in[3];
    const int* src_ms = (const int*)d_in[4];
    const int* dst_ms = (const int*)d_in[5];
    const int* lbl_row = (const int*)d_in[6];
    const int* lbl_col = (const int*)d_in[7];
    const float* W1l_sm = (const float*)d_in[8];
    const float* W1r_sm = (const float*)d_in[9];
    const float* W1l_ms = (const float*)d_in[10];
    const float* W1r_ms = (const float*)d_in[11];
    const float* W2l_sm = (const float*)d_in[12];
    const float* W2r_sm = (const float*)d_in[13];
    const float* W2l_ms = (const float*)d_in[14];
    const float* W2r_ms = (const float*)d_in[15];
    const float* b1_sm = (const float*)d_in[16];
    const float* b1_ms = (const float*)d_in[17];
    const float* b2_sm = (const float*)d_in[18];
    const float* b2_ms = (const float*)d_in[19];
    float* out = (float*)d_out;

    // Workspace layout (16B aligned)
    char* ws = (char*)d_ws;
    unsigned short* xS_bf   = (unsigned short*)(ws + 0);           //   5,120,000
    unsigned short* xM_bf   = (unsigned short*)(ws + 5120000);     //  25,600,000
    unsigned short* meanM   = (unsigned short*)(ws + 30720000);    //  25,600,000 (becomes zM)
    unsigned short* meanS   = (unsigned short*)(ws + 56320000);    //   5,120,000 (becomes zS)
    unsigned short* hM_bf   = (unsigned short*)(ws + 61440000);    //  25,600,000
    unsigned short* hS_bf   = (unsigned short*)(ws + 87040000);    //   5,120,000
    unsigned short* Wt1sm   = (unsigned short*)(ws + 92160000);    //      65,536
    unsigned short* Wt1ms   = (unsigned short*)(ws + 92225536);    //      65,536
    unsigned short* Wt2sm   = (unsigned short*)(ws + 92291072);    //      65,536
    unsigned short* Wt2ms   = (unsigned short*)(ws + 92356608);    //      65,536
    int* begd               = (int*)(ws + 92422144);               //     480,000
    int* degd               = (int*)(ws + 92902144);               //     480,000
    int* col_all            = (int*)(ws + 93382144);               //  11,567,104 (353*8192*4)
    unsigned int* recs      = (unsigned int*)(ws + 104949248);     //  11,567,104
    uint2* qrecs            = (uint2*)(ws + 116516352);            //   6,422,528 (196*4096*8)
    uint2* qdat             = (uint2*)(ws + 122938880);            //   6,422,528
    int* qbeg               = (int*)(ws + 129361408);              //     400,000
    int* qdeg               = (int*)(ws + 129761408);              //     400,000
    int* bcur               = (int*)(ws + 130161408);              //       1,412 (353 ints)
    int* qbcur              = (int*)(ws + 130162820);              //         784 (196 ints)
    // total ~130.2 MB

    // --- dtype prep ---
    k_cvt_bf<<<2048, 256, 0, stream>>>(x_srna, xS_bf, N_SRNA * FDIM / 4);
    k_cvt_bf<<<2048, 256, 0, stream>>>(x_mrna, xM_bf, N_MRNA * FDIM / 4);
    k_build_wt4<<<512, 256, 0, stream>>>(W1l_sm, W1r_sm, Wt1sm,
                                         W1l_ms, W1r_ms, Wt1ms,
                                         W2l_sm, W2r_sm, Wt2sm,
                                         W2l_ms, W2r_ms, Wt2ms);

    // --- zero both cursor arrays with ONE memset (adjacent) ---
    hipMemsetAsync(bcur, 0, (NB + NB_Q) * sizeof(int), stream);

    // --- Edge CSR (fixed-capacity buckets) ---
    const int nblk = (2 * NE + 4095) / 4096;               // 489
    k_bscatter<<<nblk, 256, 0, stream>>>(src_sm, dst_sm, src_ms, dst_ms, bcur, recs);
    k_bbuild<<<NB, 256, 0, stream>>>(recs, bcur, begd, degd, col_all);

    // --- Query CSR ---
    const int nqblk = (NQ + 4095) / 4096;                  // 123
    k_qscatter<<<nqblk, 256, 0, stream>>>(lbl_row, lbl_col, qbcur, qrecs);
    k_qbbuild<<<NB_Q, 256, 0, stream>>>(qrecs, qbcur, qbeg, qdeg, qdat);

    const int nblk_m = (N_MRNA + 127) / 128;               // 782
    const int nblk_s = (N_SRNA + 127) / 128;               // 157
    const int segblk = (NDST_ALL * 64 + 255) / 256;        // 30000

    // --- Layer 1 (fused node types) ---
    k_seg_mean2<<<segblk, 256, 0, stream>>>(xS_bf, xM_bf, begd, degd, col_all,
                                            meanM, meanS, N_MRNA, NDST_ALL);
    k_gemm_mfma2<true><<<nblk_m + nblk_s, 256, 0, stream>>>(
        meanM, xM_bf, Wt1sm, b1_sm, hM_bf, N_MRNA, nblk_m,
        meanS, xS_bf, Wt1ms, b1_ms, hS_bf, N_SRNA);

    // --- Layer 2 (z overwrites mean buffers in place) ---
    k_seg_mean2<<<segblk, 256, 0, stream>>>(hS_bf, hM_bf, begd, degd, col_all,
                                            meanM, meanS, N_MRNA, NDST_ALL);
    k_gemm_mfma2<false><<<nblk_m + nblk_s, 256, 0, stream>>>(
        meanM, hM_bf, Wt2sm, b2_sm, meanM, N_MRNA, nblk_m,
        meanS, hS_bf, Wt2ms, b2_ms, meanS, N_SRNA);

    // --- Decoder ---
    k_decoder_csr<<<(N_MRNA + 3) / 4, 256, 0, stream>>>(meanS, meanM, qbeg, qdeg, qdat, out);
}

// Round 9
// 411.429 us; speedup vs baseline: 1.3501x; 1.0922x over previous
//
#include <hip/hip_runtime.h>

// Problem constants (fixed by the reference)
#define N_SRNA  20000
#define N_MRNA  100000
#define FDIM    128
#define NE      1000000
#define NQ      500000
#define NDST_ALL (N_MRNA + N_SRNA)

// Fixed-capacity buckets (no hist/scan prepass); see round-5 sigma analysis.
#define NB_M 196
#define NB_S 157
#define NB   (NB_M + NB_S)            // 353
#define NB_Q 196
#define ECAP 8192
#define QCAP 4096
#define NBLK_E 489                    // (2*NE + 4095) / 4096
#define NBLK_Q 123                    // (NQ + 4095) / 4096

typedef __attribute__((ext_vector_type(8))) short bf16x8;
typedef __attribute__((ext_vector_type(4))) float f32x4;

__device__ __forceinline__ unsigned short f2bf(float f) {
    unsigned int u = __float_as_uint(f);
    unsigned int r = (u + 0x7fffu + ((u >> 16) & 1u)) >> 16;   // RNE
    return (unsigned short)r;
}
__device__ __forceinline__ float bf2f(unsigned short h) {
    return __uint_as_float((unsigned int)h << 16);
}

// ---------------------------------------------------------------------------
// Combined binning scatter: blocks [0,NBLK_E) bin edges, [NBLK_E,..) bin
// queries. Fixed-capacity bucket windows; cursors pre-zeroed by memset.
// ---------------------------------------------------------------------------
__global__ __launch_bounds__(256) void k_scatter_all(const int* __restrict__ src_sm,
                                                     const int* __restrict__ dst_sm,
                                                     const int* __restrict__ src_ms,
                                                     const int* __restrict__ dst_ms,
                                                     const int* __restrict__ lbl_row,
                                                     const int* __restrict__ lbl_col,
                                                     int* __restrict__ bcur,
                                                     int* __restrict__ qbcur,
                                                     unsigned int* __restrict__ recs,
                                                     uint2* __restrict__ qrecs) {
    __shared__ int lh[NB], gb[NB], lc[NB];
    int t = threadIdx.x;
    if ((int)blockIdx.x < NBLK_E) {
        for (int i = t; i < NB; i += 256) { lh[i] = 0; lc[i] = 0; }
        __syncthreads();
        unsigned int rec[16];
        int bk[16];
        int i0 = blockIdx.x * 4096;
#pragma unroll
        for (int j = 0; j < 16; ++j) {
            int i = i0 + j * 256 + t;
            int b = -1; unsigned int r = 0;
            if (i < NE) {
                int d = dst_sm[i];
                b = d >> 9;
                r = ((unsigned int)(d - (b << 9)) << 17) | (unsigned int)src_sm[i];
            } else if (i < 2 * NE) {
                int jj = i - NE;
                int d = dst_ms[jj];
                int bs = d >> 7;
                b = NB_M + bs;
                r = ((unsigned int)(d - (bs << 7)) << 17) | (unsigned int)src_ms[jj];
            }
            bk[j] = b; rec[j] = r;
            if (b >= 0) atomicAdd(&lh[b], 1);
        }
        __syncthreads();
        for (int i = t; i < NB; i += 256)
            gb[i] = lh[i] ? atomicAdd(&bcur[i], lh[i]) : 0;
        __syncthreads();
#pragma unroll
        for (int j = 0; j < 16; ++j) {
            int b = bk[j];
            if (b >= 0) {
                int slot = atomicAdd(&lc[b], 1);
                recs[(size_t)b * ECAP + gb[b] + slot] = rec[j];
            }
        }
    } else {
        for (int i = t; i < NB_Q; i += 256) { lh[i] = 0; lc[i] = 0; }
        __syncthreads();
        uint2 rec[16];
        int bk[16];
        int i0 = ((int)blockIdx.x - NBLK_E) * 4096;
#pragma unroll
        for (int j = 0; j < 16; ++j) {
            int i = i0 + j * 256 + t;
            int b = -1; uint2 r = make_uint2(0, 0);
            if (i < NQ) {
                int c = lbl_col[i];
                b = c >> 9;
                r.x = (unsigned int)i;
                r.y = ((unsigned int)(c - (b << 9)) << 15) | (unsigned int)lbl_row[i];
            }
            bk[j] = b; rec[j] = r;
            if (b >= 0) atomicAdd(&lh[b], 1);
        }
        __syncthreads();
        for (int i = t; i < NB_Q; i += 256)
            gb[i] = lh[i] ? atomicAdd(&qbcur[i], lh[i]) : 0;
        __syncthreads();
#pragma unroll
        for (int j = 0; j < 16; ++j) {
            int b = bk[j];
            if (b >= 0) {
                int slot = atomicAdd(&lc[b], 1);
                qrecs[(size_t)b * QCAP + gb[b] + slot] = rec[j];
            }
        }
    }
}

// ---------------------------------------------------------------------------
// Combined per-bucket CSR finalize: blocks [0,NB) edge buckets, rest query.
// ---------------------------------------------------------------------------
__global__ __launch_bounds__(256) void k_build_all(const unsigned int* __restrict__ recs,
                                                   const int* __restrict__ bcur,
                                                   const uint2* __restrict__ qrecs,
                                                   const int* __restrict__ qbcur,
                                                   int* __restrict__ begd,
                                                   int* __restrict__ degd,
                                                   int* __restrict__ col,
                                                   int* __restrict__ qbeg,
                                                   int* __restrict__ qdeg,
                                                   uint2* __restrict__ qdat) {
    __shared__ int lh[512], lptr[512], lps[256];
    const int t = threadIdx.x;
    if ((int)blockIdx.x < NB) {
        const int b = blockIdx.x;
        const int nd = (b < NB_M) ? min(512, N_MRNA - (b << 9))
                                  : min(128, N_SRNA - ((b - NB_M) << 7));
        const int dst0 = (b < NB_M) ? (b << 9) : N_MRNA + ((b - NB_M) << 7);
        const int base = b * ECAP;
        const int nbe = bcur[b];

        lh[t] = 0; lh[t + 256] = 0;
        __syncthreads();
        for (int e = t; e < nbe; e += 256)
            atomicAdd(&lh[recs[(size_t)base + e] >> 17], 1);
        __syncthreads();

        int a0 = lh[2 * t], a1 = lh[2 * t + 1];
        int ps = a0 + a1;
        lps[t] = ps;
        __syncthreads();
        for (int off = 1; off < 256; off <<= 1) {
            int x = (t >= off) ? lps[t - off] : 0;
            __syncthreads();
            lps[t] += x;
            __syncthreads();
        }
        int ex = lps[t] - ps;
        lptr[2 * t] = ex;
        lptr[2 * t + 1] = ex + a0;
        __syncthreads();

        for (int d = t; d < nd; d += 256) {
            begd[dst0 + d] = base + lptr[d];
            degd[dst0 + d] = lh[d];
        }
        __syncthreads();
        lh[t] = lptr[t]; lh[t + 256] = lptr[t + 256];
        __syncthreads();
        for (int e = t; e < nbe; e += 256) {
            unsigned int r = recs[(size_t)base + e];
            int slot = atomicAdd(&lh[r >> 17], 1);
            col[base + slot] = (int)(r & 0x1FFFFu);
        }
    } else {
        const int b = blockIdx.x - NB;
        const int nd = min(512, N_MRNA - (b << 9));
        const int col0 = b << 9;
        const int base = b * QCAP;
        const int nbe = qbcur[b];

        lh[t] = 0; lh[t + 256] = 0;
        __syncthreads();
        for (int e = t; e < nbe; e += 256)
            atomicAdd(&lh[qrecs[(size_t)base + e].y >> 15], 1);
        __syncthreads();

        int a0 = lh[2 * t], a1 = lh[2 * t + 1];
        int ps = a0 + a1;
        lps[t] = ps;
        __syncthreads();
        for (int off = 1; off < 256; off <<= 1) {
            int x = (t >= off) ? lps[t - off] : 0;
            __syncthreads();
            lps[t] += x;
            __syncthreads();
        }
        int ex = lps[t] - ps;
        lptr[2 * t] = ex;
        lptr[2 * t + 1] = ex + a0;
        __syncthreads();

        for (int d = t; d < nd; d += 256) {
            qbeg[col0 + d] = base + lptr[d];
            qdeg[col0 + d] = lh[d];
        }
        __syncthreads();
        lh[t] = lptr[t]; lh[t + 256] = lptr[t + 256];
        __syncthreads();
        for (int e = t; e < nbe; e += 256) {
            uint2 r = qrecs[(size_t)base + e];
            int slot = atomicAdd(&lh[r.y >> 15], 1);
            qdat[base + slot] = make_uint2(r.y & 0x7FFFu, r.x);   // {row, qidx}
        }
    }
}

// ---------------------------------------------------------------------------
// Combined fp32 -> bf16 conversion for both feature matrices.
// ---------------------------------------------------------------------------
__global__ __launch_bounds__(256) void k_cvt_all(const float* __restrict__ xs,
                                                 const float* __restrict__ xm,
                                                 unsigned short* __restrict__ oS,
                                                 unsigned short* __restrict__ oM) {
    const int nS4 = N_SRNA * FDIM / 4;     // 640000
    const int nT4 = NDST_ALL * FDIM / 4;   // 3840000
    int i = blockIdx.x * 256 + threadIdx.x;
    int stride = gridDim.x * 256;
    for (; i < nT4; i += stride) {
        if (i < nS4) {
            float4 v = ((const float4*)xs)[i];
            unsigned int p0 = (unsigned int)f2bf(v.x) | ((unsigned int)f2bf(v.y) << 16);
            unsigned int p1 = (unsigned int)f2bf(v.z) | ((unsigned int)f2bf(v.w) << 16);
            ((uint2*)oS)[i] = make_uint2(p0, p1);
        } else {
            int j = i - nS4;
            float4 v = ((const float4*)xm)[j];
            unsigned int p0 = (unsigned int)f2bf(v.x) | ((unsigned int)f2bf(v.y) << 16);
            unsigned int p1 = (unsigned int)f2bf(v.z) | ((unsigned int)f2bf(v.w) << 16);
            ((uint2*)oM)[j] = make_uint2(p0, p1);
        }
    }
}

// Wt[c][k] = bf16(k<128 ? Wl[k][c] : Wr[k-128][c]); 4 weight sets, 128 blocks each.
__global__ __launch_bounds__(256) void k_build_wt4(
        const float* __restrict__ Wl0, const float* __restrict__ Wr0, unsigned short* __restrict__ Wt0,
        const float* __restrict__ Wl1, const float* __restrict__ Wr1, unsigned short* __restrict__ Wt1,
        const float* __restrict__ Wl2, const float* __restrict__ Wr2, unsigned short* __restrict__ Wt2,
        const float* __restrict__ Wl3, const float* __restrict__ Wr3, unsigned short* __restrict__ Wt3) {
    int g = blockIdx.x >> 7;
    const float* Wl; const float* Wr; unsigned short* Wt;
    if (g == 0)      { Wl = Wl0; Wr = Wr0; Wt = Wt0; }
    else if (g == 1) { Wl = Wl1; Wr = Wr1; Wt = Wt1; }
    else if (g == 2) { Wl = Wl2; Wr = Wr2; Wt = Wt2; }
    else             { Wl = Wl3; Wr = Wr3; Wt = Wt3; }
    int tid = (blockIdx.x & 127) * 256 + threadIdx.x;   // 0..32767
    int c = tid & 127, k = tid >> 7;
    float v = (k < 128) ? Wl[k * 128 + c] : Wr[(k - 128) * 128 + c];
    Wt[c * 256 + k] = f2bf(v);
}

// ---------------------------------------------------------------------------
// Segment mean, row-per-quarter: each 16-lane quarter owns one dst row
// (16 lanes x 16B = full 128-feature row). 4 rows per wave concurrently,
// main loop unrolled x4 -> up to 16 row-gathers in flight per wave. No
// cross-quarter reduce, no clamped dummy loads.
// ---------------------------------------------------------------------------
__global__ __launch_bounds__(256) void k_seg_mean2(const unsigned short* __restrict__ srcA,
                                                   const unsigned short* __restrict__ srcB,
                                                   const int* __restrict__ begd,
                                                   const int* __restrict__ degd,
                                                   const int* __restrict__ cols,
                                                   unsigned short* __restrict__ outA,
                                                   unsigned short* __restrict__ outB,
                                                   int nA, int nTot) {
    int wave = (blockIdx.x * 256 + threadIdx.x) >> 6;
    int l = threadIdx.x & 63;
    const int q = l >> 4, lq = l & 15;
    int r = wave * 4 + q;
    bool rowok = r < nTot;
    int rr = rowok ? r : 0;
    const unsigned short* xs = (rr < nA) ? srcA : srcB;
    unsigned short* o = (rr < nA) ? (outA + (size_t)rr * FDIM)
                                  : (outB + (size_t)(rr - nA) * FDIM);
    int beg = begd[rr];
    int deg = rowok ? degd[rr] : 0;

    float acc[8];
#pragma unroll
    for (int k = 0; k < 8; ++k) acc[k] = 0.f;

    int e = 0;
    for (; e + 4 <= deg; e += 4) {
        int s0 = cols[beg + e];
        int s1 = cols[beg + e + 1];
        int s2 = cols[beg + e + 2];
        int s3 = cols[beg + e + 3];
        bf16x8 v0 = *(const bf16x8*)(xs + (size_t)s0 * FDIM + lq * 8);
        bf16x8 v1 = *(const bf16x8*)(xs + (size_t)s1 * FDIM + lq * 8);
        bf16x8 v2 = *(const bf16x8*)(xs + (size_t)s2 * FDIM + lq * 8);
        bf16x8 v3 = *(const bf16x8*)(xs + (size_t)s3 * FDIM + lq * 8);
#pragma unroll
        for (int k = 0; k < 8; ++k) acc[k] += bf2f((unsigned short)v0[k]);
#pragma unroll
        for (int k = 0; k < 8; ++k) acc[k] += bf2f((unsigned short)v1[k]);
#pragma unroll
        for (int k = 0; k < 8; ++k) acc[k] += bf2f((unsigned short)v2[k]);
#pragma unroll
        for (int k = 0; k < 8; ++k) acc[k] += bf2f((unsigned short)v3[k]);
    }
    for (; e < deg; ++e) {
        int s = cols[beg + e];
        bf16x8 v = *(const bf16x8*)(xs + (size_t)s * FDIM + lq * 8);
#pragma unroll
        for (int k = 0; k < 8; ++k) acc[k] += bf2f((unsigned short)v[k]);
    }

    if (rowok) {
        float inv = 1.0f / fmaxf((float)deg, 1.0f);
        uint4 pv;
        pv.x = (unsigned int)f2bf(acc[0] * inv) | ((unsigned int)f2bf(acc[1] * inv) << 16);
        pv.y = (unsigned int)f2bf(acc[2] * inv) | ((unsigned int)f2bf(acc[3] * inv) << 16);
        pv.z = (unsigned int)f2bf(acc[4] * inv) | ((unsigned int)f2bf(acc[5] * inv) << 16);
        pv.w = (unsigned int)f2bf(acc[6] * inv) | ((unsigned int)f2bf(acc[7] * inv) << 16);
        ((uint4*)o)[lq] = pv;
    }
}

// ---------------------------------------------------------------------------
// MFMA GEMM, both node types fused in one dispatch (unchanged from round 7).
// ---------------------------------------------------------------------------
template <bool RELU>
__global__ __launch_bounds__(256, 2) void k_gemm_mfma2(
        const unsigned short* __restrict__ A0a, const unsigned short* __restrict__ A1a,
        const unsigned short* __restrict__ Wta, const float* __restrict__ biasa,
        unsigned short* __restrict__ outa, int na, int nblka,
        const unsigned short* __restrict__ A0b, const unsigned short* __restrict__ A1b,
        const unsigned short* __restrict__ Wtb, const float* __restrict__ biasb,
        unsigned short* __restrict__ outb, int nb) {
    __shared__ uint4 smem4[4352];
    char* smem = (char*)smem4;

    const unsigned short *A0, *A1, *Wt;
    const float* bias;
    unsigned short* out;
    int n, bid;
    if ((int)blockIdx.x < nblka) {
        A0 = A0a; A1 = A1a; Wt = Wta; bias = biasa; out = outa; n = na; bid = blockIdx.x;
    } else {
        A0 = A0b; A1 = A1b; Wt = Wtb; bias = biasb; out = outb; n = nb; bid = blockIdx.x - nblka;
    }

    const int t = threadIdx.x;
#pragma unroll
    for (int i = 0; i < 16; ++i) {
        int j = i * 256 + t;
        int byteo = j << 4;
        int c = byteo >> 9;
        int off = byteo & 511;
        int swz = off ^ ((c & 7) << 4);
        uint4 v = ((const uint4*)Wt)[j];
        *(uint4*)(smem + c * 512 + swz) = v;
    }
    __syncthreads();

    const int w = t >> 6, l = t & 63;
    const int wr = w >> 1, wc = w & 1;
    const int rowbase = bid * 128 + wr * 64;
    const int colbase = wc * 64;
    const int lr = l & 15;
    const int lk = (l >> 4) * 8;

    f32x4 acc[4][4];
#pragma unroll
    for (int a = 0; a < 4; ++a)
#pragma unroll
        for (int b = 0; b < 4; ++b)
#pragma unroll
            for (int e = 0; e < 4; ++e) acc[a][b][e] = 0.f;

    bf16x8 az;
#pragma unroll
    for (int e = 0; e < 8; ++e) az[e] = 0;

#pragma unroll
    for (int s = 0; s < 8; ++s) {
        const unsigned short* Abuf = (s < 4) ? A0 : A1;
        const int kk = (s & 3) * 32 + lk;
        bf16x8 afr[4];
#pragma unroll
        for (int af = 0; af < 4; ++af) {
            int row = rowbase + af * 16 + lr;
            afr[af] = (row < n) ? *(const bf16x8*)(Abuf + (size_t)row * FDIM + kk) : az;
        }
        bf16x8 bfr[4];
#pragma unroll
        for (int bf = 0; bf < 4; ++bf) {
            int c = colbase + bf * 16 + lr;
            int off = s * 64 + lk * 2;
            int swz = off ^ ((c & 7) << 4);
            bfr[bf] = *(const bf16x8*)(smem + c * 512 + swz);
        }
#pragma unroll
        for (int af = 0; af < 4; ++af)
#pragma unroll
            for (int bf = 0; bf < 4; ++bf)
                acc[af][bf] = __builtin_amdgcn_mfma_f32_16x16x32_bf16(afr[af], bfr[bf],
                                                                      acc[af][bf], 0, 0, 0);
    }

    __syncthreads();
    float* sD = (float*)(smem + w * 17408);

#pragma unroll
    for (int af = 0; af < 4; ++af)
#pragma unroll
        for (int bf = 0; bf < 4; ++bf)
#pragma unroll
            for (int r = 0; r < 4; ++r)
                sD[(af * 16 + (l >> 4) * 4 + r) * 68 + bf * 16 + lr] = acc[af][bf][r];

#pragma unroll
    for (int j = 0; j < 8; ++j) {
        int flat = j * 512 + l * 8;
        int row = flat >> 6;
        int c0 = flat & 63;
        int grow = rowbase + row;
        if (grow >= n) continue;
        float4 v0 = *(float4*)(&sD[row * 68 + c0]);
        float4 v1 = *(float4*)(&sD[row * 68 + c0 + 4]);
        int gc = colbase + c0;
        float4 b0 = *(const float4*)(bias + gc);
        float4 b1 = *(const float4*)(bias + gc + 4);
        float o[8] = {v0.x + b0.x, v0.y + b0.y, v0.z + b0.z, v0.w + b0.w,
                      v1.x + b1.x, v1.y + b1.y, v1.z + b1.z, v1.w + b1.w};
        if (RELU) {
#pragma unroll
            for (int e = 0; e < 8; ++e) o[e] = fmaxf(o[e], 0.f);
        }
        uint4 pv;
        pv.x = (unsigned int)f2bf(o[0]) | ((unsigned int)f2bf(o[1]) << 16);
        pv.y = (unsigned int)f2bf(o[2]) | ((unsigned int)f2bf(o[3]) << 16);
        pv.z = (unsigned int)f2bf(o[4]) | ((unsigned int)f2bf(o[5]) << 16);
        pv.w = (unsigned int)f2bf(o[6]) | ((unsigned int)f2bf(o[7]) << 16);
        *(uint4*)(out + (size_t)grow * FDIM + gc) = pv;
    }
}

// ---------------------------------------------------------------------------
// CSR decoder, quarter-wave (unchanged from round 7).
// ---------------------------------------------------------------------------
__global__ __launch_bounds__(256) void k_decoder_csr(const unsigned short* __restrict__ zS,
                                                     const unsigned short* __restrict__ zM,
                                                     const int* __restrict__ qbeg,
                                                     const int* __restrict__ qdeg,
                                                     const uint2* __restrict__ qdat,
                                                     float* __restrict__ out) {
    int c = (blockIdx.x * 256 + threadIdx.x) >> 6;
    int l = threadIdx.x & 63;
    if (c >= N_MRNA) return;
    int cnt = qdeg[c];
    if (cnt == 0) return;
    int beg = qbeg[c];
    const int q = l >> 4, lq = l & 15;

    bf16x8 vm = *(const bf16x8*)(zM + (size_t)c * FDIM + lq * 8);
    float mxf[8];
#pragma unroll
    for (int k = 0; k < 8; ++k) mxf[k] = bf2f((unsigned short)vm[k]);

    for (int e = 0; e < cnt; e += 4) {
        bool valid = (e + q) < cnt;
        int idx = beg + min(e + q, cnt - 1);
        uint2 d = qdat[idx];
        bf16x8 va = *(const bf16x8*)(zS + (size_t)d.x * FDIM + lq * 8);
        float s = 0.f;
#pragma unroll
        for (int k = 0; k < 8; ++k) s += bf2f((unsigned short)va[k]) * mxf[k];
        s += __shfl_xor(s, 1);
        s += __shfl_xor(s, 2);
        s += __shfl_xor(s, 4);
        s += __shfl_xor(s, 8);
        if (valid && lq == 0) out[d.y] = s;
    }
}

// ---------------------------------------------------------------------------
// Launch
// ---------------------------------------------------------------------------
extern "C" void kernel_launch(void* const* d_in, const int* in_sizes, int n_in,
                              void* d_out, int out_size, void* d_ws, size_t ws_size,
                              hipStream_t stream) {
    const float* x_srna = (const float*)d_in[0];
    const float* x_mrna = (const float*)d_in[1];
    const int* src_sm = (const int*)d_in[2];
    const int* dst_sm = (const int*)d_in[3];
    const int* src_ms = (const int*)d_in[4];
    const int* dst_ms = (const int*)d_in[5];
    const int* lbl_row = (const int*)d_in[6];
    const int* lbl_col = (const int*)d_in[7];
    const float* W1l_sm = (const float*)d_in[8];
    const float* W1r_sm = (const float*)d_in[9];
    const float* W1l_ms = (const float*)d_in[10];
    const float* W1r_ms = (const float*)d_in[11];
    const float* W2l_sm = (const float*)d_in[12];
    const float* W2r_sm = (const float*)d_in[13];
    const float* W2l_ms = (const float*)d_in[14];
    const float* W2r_ms = (const float*)d_in[15];
    const float* b1_sm = (const float*)d_in[16];
    const float* b1_ms = (const float*)d_in[17];
    const float* b2_sm = (const float*)d_in[18];
    const float* b2_ms = (const float*)d_in[19];
    float* out = (float*)d_out;

    // Workspace layout (16B aligned)
    char* ws = (char*)d_ws;
    unsigned short* xS_bf   = (unsigned short*)(ws + 0);           //   5,120,000
    unsigned short* xM_bf   = (unsigned short*)(ws + 5120000);     //  25,600,000
    unsigned short* meanM   = (unsigned short*)(ws + 30720000);    //  25,600,000 (becomes zM)
    unsigned short* meanS   = (unsigned short*)(ws + 56320000);    //   5,120,000 (becomes zS)
    unsigned short* hM_bf   = (unsigned short*)(ws + 61440000);    //  25,600,000
    unsigned short* hS_bf   = (unsigned short*)(ws + 87040000);    //   5,120,000
    unsigned short* Wt1sm   = (unsigned short*)(ws + 92160000);    //      65,536
    unsigned short* Wt1ms   = (unsigned short*)(ws + 92225536);    //      65,536
    unsigned short* Wt2sm   = (unsigned short*)(ws + 92291072);    //      65,536
    unsigned short* Wt2ms   = (unsigned short*)(ws + 92356608);    //      65,536
    int* begd               = (int*)(ws + 92422144);               //     480,000
    int* degd               = (int*)(ws + 92902144);               //     480,000
    int* col_all            = (int*)(ws + 93382144);               //  11,567,104 (353*8192*4)
    unsigned int* recs      = (unsigned int*)(ws + 104949248);     //  11,567,104
    uint2* qrecs            = (uint2*)(ws + 116516352);            //   6,422,528 (196*4096*8)
    uint2* qdat             = (uint2*)(ws + 122938880);            //   6,422,528
    int* qbeg               = (int*)(ws + 129361408);              //     400,000
    int* qdeg               = (int*)(ws + 129761408);              //     400,000
    int* bcur               = (int*)(ws + 130161408);              //       1,412 (353 ints)
    int* qbcur              = (int*)(ws + 130162820);              //         784 (196 ints)
    // total ~130.2 MB

    // --- dtype prep ---
    k_cvt_all<<<2048, 256, 0, stream>>>(x_srna, x_mrna, xS_bf, xM_bf);
    k_build_wt4<<<512, 256, 0, stream>>>(W1l_sm, W1r_sm, Wt1sm,
                                         W1l_ms, W1r_ms, Wt1ms,
                                         W2l_sm, W2r_sm, Wt2sm,
                                         W2l_ms, W2r_ms, Wt2ms);

    // --- zero both cursor arrays with ONE memset (adjacent) ---
    hipMemsetAsync(bcur, 0, (NB + NB_Q) * sizeof(int), stream);

    // --- Combined edge + query binning, then combined finalize ---
    k_scatter_all<<<NBLK_E + NBLK_Q, 256, 0, stream>>>(src_sm, dst_sm, src_ms, dst_ms,
                                                       lbl_row, lbl_col, bcur, qbcur,
                                                       recs, qrecs);
    k_build_all<<<NB + NB_Q, 256, 0, stream>>>(recs, bcur, qrecs, qbcur,
                                               begd, degd, col_all, qbeg, qdeg, qdat);

    const int nblk_m = (N_MRNA + 127) / 128;               // 782
    const int nblk_s = (N_SRNA + 127) / 128;               // 157
    const int segblk = (NDST_ALL + 15) / 16;               // 7500 (4 rows/wave, 4 waves/blk)

    // --- Layer 1 (fused node types) ---
    k_seg_mean2<<<segblk, 256, 0, stream>>>(xS_bf, xM_bf, begd, degd, col_all,
                                            meanM, meanS, N_MRNA, NDST_ALL);
    k_gemm_mfma2<true><<<nblk_m + nblk_s, 256, 0, stream>>>(
        meanM, xM_bf, Wt1sm, b1_sm, hM_bf, N_MRNA, nblk_m,
        meanS, xS_bf, Wt1ms, b1_ms, hS_bf, N_SRNA);

    // --- Layer 2 (z overwrites mean buffers in place) ---
    k_seg_mean2<<<segblk, 256, 0, stream>>>(hS_bf, hM_bf, begd, degd, col_all,
                                            meanM, meanS, N_MRNA, NDST_ALL);
    k_gemm_mfma2<false><<<nblk_m + nblk_s, 256, 0, stream>>>(
        meanM, hM_bf, Wt2sm, b2_sm, meanM, N_MRNA, nblk_m,
        meanS, hS_bf, Wt2ms, b2_ms, meanS, N_SRNA);

    // --- Decoder ---
    k_decoder_csr<<<(N_MRNA + 3) / 4, 256, 0, stream>>>(meanS, meanM, qbeg, qdeg, qdat, out);
}

// Round 10
// 406.687 us; speedup vs baseline: 1.3658x; 1.0117x over previous
//
#include <hip/hip_runtime.h>

// Problem constants (fixed by the reference)
#define N_SRNA  20000
#define N_MRNA  100000
#define FDIM    128
#define NE      1000000
#define NQ      500000
#define NDST_ALL (N_MRNA + N_SRNA)

// Fixed-capacity buckets (no hist/scan prepass); see round-5 sigma analysis.
#define NB_M 196
#define NB_S 157
#define NB   (NB_M + NB_S)            // 353
#define NB_Q 196
#define ECAP 8192
#define QCAP 4096
#define NBLK_E 489                    // (2*NE + 4095) / 4096
#define NBLK_Q 123                    // (NQ + 4095) / 4096

typedef __attribute__((ext_vector_type(8))) short bf16x8;
typedef __attribute__((ext_vector_type(4))) float f32x4;

__device__ __forceinline__ unsigned short f2bf(float f) {
    unsigned int u = __float_as_uint(f);
    unsigned int r = (u + 0x7fffu + ((u >> 16) & 1u)) >> 16;   // RNE
    return (unsigned short)r;
}
__device__ __forceinline__ float bf2f(unsigned short h) {
    return __uint_as_float((unsigned int)h << 16);
}

// ---------------------------------------------------------------------------
// Combined binning scatter (unchanged from round 9)
// ---------------------------------------------------------------------------
__global__ __launch_bounds__(256) void k_scatter_all(const int* __restrict__ src_sm,
                                                     const int* __restrict__ dst_sm,
                                                     const int* __restrict__ src_ms,
                                                     const int* __restrict__ dst_ms,
                                                     const int* __restrict__ lbl_row,
                                                     const int* __restrict__ lbl_col,
                                                     int* __restrict__ bcur,
                                                     int* __restrict__ qbcur,
                                                     unsigned int* __restrict__ recs,
                                                     uint2* __restrict__ qrecs) {
    __shared__ int lh[NB], gb[NB], lc[NB];
    int t = threadIdx.x;
    if ((int)blockIdx.x < NBLK_E) {
        for (int i = t; i < NB; i += 256) { lh[i] = 0; lc[i] = 0; }
        __syncthreads();
        unsigned int rec[16];
        int bk[16];
        int i0 = blockIdx.x * 4096;
#pragma unroll
        for (int j = 0; j < 16; ++j) {
            int i = i0 + j * 256 + t;
            int b = -1; unsigned int r = 0;
            if (i < NE) {
                int d = dst_sm[i];
                b = d >> 9;
                r = ((unsigned int)(d - (b << 9)) << 17) | (unsigned int)src_sm[i];
            } else if (i < 2 * NE) {
                int jj = i - NE;
                int d = dst_ms[jj];
                int bs = d >> 7;
                b = NB_M + bs;
                r = ((unsigned int)(d - (bs << 7)) << 17) | (unsigned int)src_ms[jj];
            }
            bk[j] = b; rec[j] = r;
            if (b >= 0) atomicAdd(&lh[b], 1);
        }
        __syncthreads();
        for (int i = t; i < NB; i += 256)
            gb[i] = lh[i] ? atomicAdd(&bcur[i], lh[i]) : 0;
        __syncthreads();
#pragma unroll
        for (int j = 0; j < 16; ++j) {
            int b = bk[j];
            if (b >= 0) {
                int slot = atomicAdd(&lc[b], 1);
                recs[(size_t)b * ECAP + gb[b] + slot] = rec[j];
            }
        }
    } else {
        for (int i = t; i < NB_Q; i += 256) { lh[i] = 0; lc[i] = 0; }
        __syncthreads();
        uint2 rec[16];
        int bk[16];
        int i0 = ((int)blockIdx.x - NBLK_E) * 4096;
#pragma unroll
        for (int j = 0; j < 16; ++j) {
            int i = i0 + j * 256 + t;
            int b = -1; uint2 r = make_uint2(0, 0);
            if (i < NQ) {
                int c = lbl_col[i];
                b = c >> 9;
                r.x = (unsigned int)i;
                r.y = ((unsigned int)(c - (b << 9)) << 15) | (unsigned int)lbl_row[i];
            }
            bk[j] = b; rec[j] = r;
            if (b >= 0) atomicAdd(&lh[b], 1);
        }
        __syncthreads();
        for (int i = t; i < NB_Q; i += 256)
            gb[i] = lh[i] ? atomicAdd(&qbcur[i], lh[i]) : 0;
        __syncthreads();
#pragma unroll
        for (int j = 0; j < 16; ++j) {
            int b = bk[j];
            if (b >= 0) {
                int slot = atomicAdd(&lc[b], 1);
                qrecs[(size_t)b * QCAP + gb[b] + slot] = rec[j];
            }
        }
    }
}

// ---------------------------------------------------------------------------
// Combined per-bucket CSR finalize (unchanged from round 9)
// ---------------------------------------------------------------------------
__global__ __launch_bounds__(256) void k_build_all(const unsigned int* __restrict__ recs,
                                                   const int* __restrict__ bcur,
                                                   const uint2* __restrict__ qrecs,
                                                   const int* __restrict__ qbcur,
                                                   int* __restrict__ begd,
                                                   int* __restrict__ degd,
                                                   int* __restrict__ col,
                                                   int* __restrict__ qbeg,
                                                   int* __restrict__ qdeg,
                                                   uint2* __restrict__ qdat) {
    __shared__ int lh[512], lptr[512], lps[256];
    const int t = threadIdx.x;
    if ((int)blockIdx.x < NB) {
        const int b = blockIdx.x;
        const int nd = (b < NB_M) ? min(512, N_MRNA - (b << 9))
                                  : min(128, N_SRNA - ((b - NB_M) << 7));
        const int dst0 = (b < NB_M) ? (b << 9) : N_MRNA + ((b - NB_M) << 7);
        const int base = b * ECAP;
        const int nbe = bcur[b];

        lh[t] = 0; lh[t + 256] = 0;
        __syncthreads();
        for (int e = t; e < nbe; e += 256)
            atomicAdd(&lh[recs[(size_t)base + e] >> 17], 1);
        __syncthreads();

        int a0 = lh[2 * t], a1 = lh[2 * t + 1];
        int ps = a0 + a1;
        lps[t] = ps;
        __syncthreads();
        for (int off = 1; off < 256; off <<= 1) {
            int x = (t >= off) ? lps[t - off] : 0;
            __syncthreads();
            lps[t] += x;
            __syncthreads();
        }
        int ex = lps[t] - ps;
        lptr[2 * t] = ex;
        lptr[2 * t + 1] = ex + a0;
        __syncthreads();

        for (int d = t; d < nd; d += 256) {
            begd[dst0 + d] = base + lptr[d];
            degd[dst0 + d] = lh[d];
        }
        __syncthreads();
        lh[t] = lptr[t]; lh[t + 256] = lptr[t + 256];
        __syncthreads();
        for (int e = t; e < nbe; e += 256) {
            unsigned int r = recs[(size_t)base + e];
            int slot = atomicAdd(&lh[r >> 17], 1);
            col[base + slot] = (int)(r & 0x1FFFFu);
        }
    } else {
        const int b = blockIdx.x - NB;
        const int nd = min(512, N_MRNA - (b << 9));
        const int col0 = b << 9;
        const int base = b * QCAP;
        const int nbe = qbcur[b];

        lh[t] = 0; lh[t + 256] = 0;
        __syncthreads();
        for (int e = t; e < nbe; e += 256)
            atomicAdd(&lh[qrecs[(size_t)base + e].y >> 15], 1);
        __syncthreads();

        int a0 = lh[2 * t], a1 = lh[2 * t + 1];
        int ps = a0 + a1;
        lps[t] = ps;
        __syncthreads();
        for (int off = 1; off < 256; off <<= 1) {
            int x = (t >= off) ? lps[t - off] : 0;
            __syncthreads();
            lps[t] += x;
            __syncthreads();
        }
        int ex = lps[t] - ps;
        lptr[2 * t] = ex;
        lptr[2 * t + 1] = ex + a0;
        __syncthreads();

        for (int d = t; d < nd; d += 256) {
            qbeg[col0 + d] = base + lptr[d];
            qdeg[col0 + d] = lh[d];
        }
        __syncthreads();
        lh[t] = lptr[t]; lh[t + 256] = lptr[t + 256];
        __syncthreads();
        for (int e = t; e < nbe; e += 256) {
            uint2 r = qrecs[(size_t)base + e];
            int slot = atomicAdd(&lh[r.y >> 15], 1);
            qdat[base + slot] = make_uint2(r.y & 0x7FFFu, r.x);   // {row, qidx}
        }
    }
}

// ---------------------------------------------------------------------------
// Merged prep: blocks [0,512) build the 4 transposed weight mats; blocks
// [512, 2560) convert both feature matrices fp32->bf16.
// ---------------------------------------------------------------------------
__global__ __launch_bounds__(256) void k_prep(
        const float* __restrict__ xs, const float* __restrict__ xm,
        unsigned short* __restrict__ oS, unsigned short* __restrict__ oM,
        const float* __restrict__ Wl0, const float* __restrict__ Wr0, unsigned short* __restrict__ Wt0,
        const float* __restrict__ Wl1, const float* __restrict__ Wr1, unsigned short* __restrict__ Wt1,
        const float* __restrict__ Wl2, const float* __restrict__ Wr2, unsigned short* __restrict__ Wt2,
        const float* __restrict__ Wl3, const float* __restrict__ Wr3, unsigned short* __restrict__ Wt3) {
    if ((int)blockIdx.x < 512) {
        int g = blockIdx.x >> 7;
        const float* Wl; const float* Wr; unsigned short* Wt;
        if (g == 0)      { Wl = Wl0; Wr = Wr0; Wt = Wt0; }
        else if (g == 1) { Wl = Wl1; Wr = Wr1; Wt = Wt1; }
        else if (g == 2) { Wl = Wl2; Wr = Wr2; Wt = Wt2; }
        else             { Wl = Wl3; Wr = Wr3; Wt = Wt3; }
        int tid = (blockIdx.x & 127) * 256 + threadIdx.x;   // 0..32767
        int c = tid & 127, k = tid >> 7;
        float v = (k < 128) ? Wl[k * 128 + c] : Wr[(k - 128) * 128 + c];
        Wt[c * 256 + k] = f2bf(v);
    } else {
        const int nS4 = N_SRNA * FDIM / 4;     // 640000
        const int nT4 = NDST_ALL * FDIM / 4;   // 3840000
        int i = ((int)blockIdx.x - 512) * 256 + threadIdx.x;
        int stride = 2048 * 256;
        for (; i < nT4; i += stride) {
            if (i < nS4) {
                float4 v = ((const float4*)xs)[i];
                unsigned int p0 = (unsigned int)f2bf(v.x) | ((unsigned int)f2bf(v.y) << 16);
                unsigned int p1 = (unsigned int)f2bf(v.z) | ((unsigned int)f2bf(v.w) << 16);
                ((uint2*)oS)[i] = make_uint2(p0, p1);
            } else {
                int j = i - nS4;
                float4 v = ((const float4*)xm)[j];
                unsigned int p0 = (unsigned int)f2bf(v.x) | ((unsigned int)f2bf(v.y) << 16);
                unsigned int p1 = (unsigned int)f2bf(v.z) | ((unsigned int)f2bf(v.w) << 16);
                ((uint2*)oM)[j] = make_uint2(p0, p1);
            }
        }
    }
}

// ---------------------------------------------------------------------------
// Segment mean, row-per-quarter with shuffle-broadcast indices: each 16-lane
// quarter owns one dst row. Per 8-edge chunk, lanes (lq&7) load 8 col indices
// in ONE coalesced load; __shfl broadcasts each within the quarter; 8
// independent row-gathers issue back-to-back (32 in flight per wave).
// Accumulation stays in edge order (i=0..7 sequential) -> same fp32 sum
// order as before.
// ---------------------------------------------------------------------------
__global__ __launch_bounds__(256) void k_seg_mean2(const unsigned short* __restrict__ srcA,
                                                   const unsigned short* __restrict__ srcB,
                                                   const int* __restrict__ begd,
                                                   const int* __restrict__ degd,
                                                   const int* __restrict__ cols,
                                                   unsigned short* __restrict__ outA,
                                                   unsigned short* __restrict__ outB,
                                                   int nA, int nTot) {
    int wave = (blockIdx.x * 256 + threadIdx.x) >> 6;
    int l = threadIdx.x & 63;
    const int q = l >> 4, lq = l & 15;
    int r = wave * 4 + q;
    bool rowok = r < nTot;
    int rr = rowok ? r : 0;
    const unsigned short* xs = (rr < nA) ? srcA : srcB;
    unsigned short* o = (rr < nA) ? (outA + (size_t)rr * FDIM)
                                  : (outB + (size_t)(rr - nA) * FDIM);
    int beg = begd[rr];
    int deg = rowok ? degd[rr] : 0;

    float acc[8];
#pragma unroll
    for (int k = 0; k < 8; ++k) acc[k] = 0.f;

    for (int e0 = 0; e0 < deg; e0 += 8) {
        int rem = deg - e0;                               // >= 1
        int ci = cols[beg + e0 + min(lq & 7, rem - 1)];   // 8 distinct addrs / quarter
        bf16x8 v[8];
#pragma unroll
        for (int i = 0; i < 8; ++i) {
            int s = __shfl(ci, i, 16);                    // broadcast within quarter
            v[i] = *(const bf16x8*)(xs + (size_t)s * FDIM + lq * 8);
        }
#pragma unroll
        for (int i = 0; i < 8; ++i) {
            if (i < rem) {
#pragma unroll
                for (int k = 0; k < 8; ++k) acc[k] += bf2f((unsigned short)v[i][k]);
            }
        }
    }

    if (rowok) {
        float inv = 1.0f / fmaxf((float)deg, 1.0f);
        uint4 pv;
        pv.x = (unsigned int)f2bf(acc[0] * inv) | ((unsigned int)f2bf(acc[1] * inv) << 16);
        pv.y = (unsigned int)f2bf(acc[2] * inv) | ((unsigned int)f2bf(acc[3] * inv) << 16);
        pv.z = (unsigned int)f2bf(acc[4] * inv) | ((unsigned int)f2bf(acc[5] * inv) << 16);
        pv.w = (unsigned int)f2bf(acc[6] * inv) | ((unsigned int)f2bf(acc[7] * inv) << 16);
        ((uint4*)o)[lq] = pv;
    }
}

// ---------------------------------------------------------------------------
// MFMA GEMM, both node types fused in one dispatch (unchanged).
// ---------------------------------------------------------------------------
template <bool RELU>
__global__ __launch_bounds__(256, 2) void k_gemm_mfma2(
        const unsigned short* __restrict__ A0a, const unsigned short* __restrict__ A1a,
        const unsigned short* __restrict__ Wta, const float* __restrict__ biasa,
        unsigned short* __restrict__ outa, int na, int nblka,
        const unsigned short* __restrict__ A0b, const unsigned short* __restrict__ A1b,
        const unsigned short* __restrict__ Wtb, const float* __restrict__ biasb,
        unsigned short* __restrict__ outb, int nb) {
    __shared__ uint4 smem4[4352];
    char* smem = (char*)smem4;

    const unsigned short *A0, *A1, *Wt;
    const float* bias;
    unsigned short* out;
    int n, bid;
    if ((int)blockIdx.x < nblka) {
        A0 = A0a; A1 = A1a; Wt = Wta; bias = biasa; out = outa; n = na; bid = blockIdx.x;
    } else {
        A0 = A0b; A1 = A1b; Wt = Wtb; bias = biasb; out = outb; n = nb; bid = blockIdx.x - nblka;
    }

    const int t = threadIdx.x;
#pragma unroll
    for (int i = 0; i < 16; ++i) {
        int j = i * 256 + t;
        int byteo = j << 4;
        int c = byteo >> 9;
        int off = byteo & 511;
        int swz = off ^ ((c & 7) << 4);
        uint4 v = ((const uint4*)Wt)[j];
        *(uint4*)(smem + c * 512 + swz) = v;
    }
    __syncthreads();

    const int w = t >> 6, l = t & 63;
    const int wr = w >> 1, wc = w & 1;
    const int rowbase = bid * 128 + wr * 64;
    const int colbase = wc * 64;
    const int lr = l & 15;
    const int lk = (l >> 4) * 8;

    f32x4 acc[4][4];
#pragma unroll
    for (int a = 0; a < 4; ++a)
#pragma unroll
        for (int b = 0; b < 4; ++b)
#pragma unroll
            for (int e = 0; e < 4; ++e) acc[a][b][e] = 0.f;

    bf16x8 az;
#pragma unroll
    for (int e = 0; e < 8; ++e) az[e] = 0;

#pragma unroll
    for (int s = 0; s < 8; ++s) {
        const unsigned short* Abuf = (s < 4) ? A0 : A1;
        const int kk = (s & 3) * 32 + lk;
        bf16x8 afr[4];
#pragma unroll
        for (int af = 0; af < 4; ++af) {
            int row = rowbase + af * 16 + lr;
            afr[af] = (row < n) ? *(const bf16x8*)(Abuf + (size_t)row * FDIM + kk) : az;
        }
        bf16x8 bfr[4];
#pragma unroll
        for (int bf = 0; bf < 4; ++bf) {
            int c = colbase + bf * 16 + lr;
            int off = s * 64 + lk * 2;
            int swz = off ^ ((c & 7) << 4);
            bfr[bf] = *(const bf16x8*)(smem + c * 512 + swz);
        }
#pragma unroll
        for (int af = 0; af < 4; ++af)
#pragma unroll
            for (int bf = 0; bf < 4; ++bf)
                acc[af][bf] = __builtin_amdgcn_mfma_f32_16x16x32_bf16(afr[af], bfr[bf],
                                                                      acc[af][bf], 0, 0, 0);
    }

    __syncthreads();
    float* sD = (float*)(smem + w * 17408);

#pragma unroll
    for (int af = 0; af < 4; ++af)
#pragma unroll
        for (int bf = 0; bf < 4; ++bf)
#pragma unroll
            for (int r = 0; r < 4; ++r)
                sD[(af * 16 + (l >> 4) * 4 + r) * 68 + bf * 16 + lr] = acc[af][bf][r];

#pragma unroll
    for (int j = 0; j < 8; ++j) {
        int flat = j * 512 + l * 8;
        int row = flat >> 6;
        int c0 = flat & 63;
        int grow = rowbase + row;
        if (grow >= n) continue;
        float4 v0 = *(float4*)(&sD[row * 68 + c0]);
        float4 v1 = *(float4*)(&sD[row * 68 + c0 + 4]);
        int gc = colbase + c0;
        float4 b0 = *(const float4*)(bias + gc);
        float4 b1 = *(const float4*)(bias + gc + 4);
        float o[8] = {v0.x + b0.x, v0.y + b0.y, v0.z + b0.z, v0.w + b0.w,
                      v1.x + b1.x, v1.y + b1.y, v1.z + b1.z, v1.w + b1.w};
        if (RELU) {
#pragma unroll
            for (int e = 0; e < 8; ++e) o[e] = fmaxf(o[e], 0.f);
        }
        uint4 pv;
        pv.x = (unsigned int)f2bf(o[0]) | ((unsigned int)f2bf(o[1]) << 16);
        pv.y = (unsigned int)f2bf(o[2]) | ((unsigned int)f2bf(o[3]) << 16);
        pv.z = (unsigned int)f2bf(o[4]) | ((unsigned int)f2bf(o[5]) << 16);
        pv.w = (unsigned int)f2bf(o[6]) | ((unsigned int)f2bf(o[7]) << 16);
        *(uint4*)(out + (size_t)grow * FDIM + gc) = pv;
    }
}

// ---------------------------------------------------------------------------
// CSR decoder, quarter-wave (unchanged).
// ---------------------------------------------------------------------------
__global__ __launch_bounds__(256) void k_decoder_csr(const unsigned short* __restrict__ zS,
                                                     const unsigned short* __restrict__ zM,
                                                     const int* __restrict__ qbeg,
                                                     const int* __restrict__ qdeg,
                                                     const uint2* __restrict__ qdat,
                                                     float* __restrict__ out) {
    int c = (blockIdx.x * 256 + threadIdx.x) >> 6;
    int l = threadIdx.x & 63;
    if (c >= N_MRNA) return;
    int cnt = qdeg[c];
    if (cnt == 0) return;
    int beg = qbeg[c];
    const int q = l >> 4, lq = l & 15;

    bf16x8 vm = *(const bf16x8*)(zM + (size_t)c * FDIM + lq * 8);
    float mxf[8];
#pragma unroll
    for (int k = 0; k < 8; ++k) mxf[k] = bf2f((unsigned short)vm[k]);

    for (int e = 0; e < cnt; e += 4) {
        bool valid = (e + q) < cnt;
        int idx = beg + min(e + q, cnt - 1);
        uint2 d = qdat[idx];
        bf16x8 va = *(const bf16x8*)(zS + (size_t)d.x * FDIM + lq * 8);
        float s = 0.f;
#pragma unroll
        for (int k = 0; k < 8; ++k) s += bf2f((unsigned short)va[k]) * mxf[k];
        s += __shfl_xor(s, 1);
        s += __shfl_xor(s, 2);
        s += __shfl_xor(s, 4);
        s += __shfl_xor(s, 8);
        if (valid && lq == 0) out[d.y] = s;
    }
}

// ---------------------------------------------------------------------------
// Launch
// ---------------------------------------------------------------------------
extern "C" void kernel_launch(void* const* d_in, const int* in_sizes, int n_in,
                              void* d_out, int out_size, void* d_ws, size_t ws_size,
                              hipStream_t stream) {
    const float* x_srna = (const float*)d_in[0];
    const float* x_mrna = (const float*)d_in[1];
    const int* src_sm = (const int*)d_in[2];
    const int* dst_sm = (const int*)d_in[3];
    const int* src_ms = (const int*)d_in[4];
    const int* dst_ms = (const int*)d_in[5];
    const int* lbl_row = (const int*)d_in[6];
    const int* lbl_col = (const int*)d_in[7];
    const float* W1l_sm = (const float*)d_in[8];
    const float* W1r_sm = (const float*)d_in[9];
    const float* W1l_ms = (const float*)d_in[10];
    const float* W1r_ms = (const float*)d_in[11];
    const float* W2l_sm = (const float*)d_in[12];
    const float* W2r_sm = (const float*)d_in[13];
    const float* W2l_ms = (const float*)d_in[14];
    const float* W2r_ms = (const float*)d_in[15];
    const float* b1_sm = (const float*)d_in[16];
    const float* b1_ms = (const float*)d_in[17];
    const float* b2_sm = (const float*)d_in[18];
    const float* b2_ms = (const float*)d_in[19];
    float* out = (float*)d_out;

    // Workspace layout (16B aligned)
    char* ws = (char*)d_ws;
    unsigned short* xS_bf   = (unsigned short*)(ws + 0);           //   5,120,000
    unsigned short* xM_bf   = (unsigned short*)(ws + 5120000);     //  25,600,000
    unsigned short* meanM   = (unsigned short*)(ws + 30720000);    //  25,600,000 (becomes zM)
    unsigned short* meanS   = (unsigned short*)(ws + 56320000);    //   5,120,000 (becomes zS)
    unsigned short* hM_bf   = (unsigned short*)(ws + 61440000);    //  25,600,000
    unsigned short* hS_bf   = (unsigned short*)(ws + 87040000);    //   5,120,000
    unsigned short* Wt1sm   = (unsigned short*)(ws + 92160000);    //      65,536
    unsigned short* Wt1ms   = (unsigned short*)(ws + 92225536);    //      65,536
    unsigned short* Wt2sm   = (unsigned short*)(ws + 92291072);    //      65,536
    unsigned short* Wt2ms   = (unsigned short*)(ws + 92356608);    //      65,536
    int* begd               = (int*)(ws + 92422144);               //     480,000
    int* degd               = (int*)(ws + 92902144);               //     480,000
    int* col_all            = (int*)(ws + 93382144);               //  11,567,104 (353*8192*4)
    unsigned int* recs      = (unsigned int*)(ws + 104949248);     //  11,567,104
    uint2* qrecs            = (uint2*)(ws + 116516352);            //   6,422,528 (196*4096*8)
    uint2* qdat             = (uint2*)(ws + 122938880);            //   6,422,528
    int* qbeg               = (int*)(ws + 129361408);              //     400,000
    int* qdeg               = (int*)(ws + 129761408);              //     400,000
    int* bcur               = (int*)(ws + 130161408);              //       1,412 (353 ints)
    int* qbcur              = (int*)(ws + 130162820);              //         784 (196 ints)
    // total ~130.2 MB

    // --- merged dtype prep (wt build + cvt in one dispatch) ---
    k_prep<<<2560, 256, 0, stream>>>(x_srna, x_mrna, xS_bf, xM_bf,
                                     W1l_sm, W1r_sm, Wt1sm,
                                     W1l_ms, W1r_ms, Wt1ms,
                                     W2l_sm, W2r_sm, Wt2sm,
                                     W2l_ms, W2r_ms, Wt2ms);

    // --- zero both cursor arrays with ONE memset (adjacent) ---
    hipMemsetAsync(bcur, 0, (NB + NB_Q) * sizeof(int), stream);

    // --- Combined edge + query binning, then combined finalize ---
    k_scatter_all<<<NBLK_E + NBLK_Q, 256, 0, stream>>>(src_sm, dst_sm, src_ms, dst_ms,
                                                       lbl_row, lbl_col, bcur, qbcur,
                                                       recs, qrecs);
    k_build_all<<<NB + NB_Q, 256, 0, stream>>>(recs, bcur, qrecs, qbcur,
                                               begd, degd, col_all, qbeg, qdeg, qdat);

    const int nblk_m = (N_MRNA + 127) / 128;               // 782
    const int nblk_s = (N_SRNA + 127) / 128;               // 157
    const int segblk = (NDST_ALL + 15) / 16;               // 7500 (4 rows/wave, 4 waves/blk)

    // --- Layer 1 (fused node types) ---
    k_seg_mean2<<<segblk, 256, 0, stream>>>(xS_bf, xM_bf, begd, degd, col_all,
                                            meanM, meanS, N_MRNA, NDST_ALL);
    k_gemm_mfma2<true><<<nblk_m + nblk_s, 256, 0, stream>>>(
        meanM, xM_bf, Wt1sm, b1_sm, hM_bf, N_MRNA, nblk_m,
        meanS, xS_bf, Wt1ms, b1_ms, hS_bf, N_SRNA);

    // --- Layer 2 (z overwrites mean buffers in place) ---
    k_seg_mean2<<<segblk, 256, 0, stream>>>(hS_bf, hM_bf, begd, degd, col_all,
                                            meanM, meanS, N_MRNA, NDST_ALL);
    k_gemm_mfma2<false><<<nblk_m + nblk_s, 256, 0, stream>>>(
        meanM, hM_bf, Wt2sm, b2_sm, meanM, N_MRNA, nblk_m,
        meanS, hS_bf, Wt2ms, b2_ms, meanS, N_SRNA);

    // --- Decoder ---
    k_decoder_csr<<<(N_MRNA + 3) / 4, 256, 0, stream>>>(meanS, meanM, qbeg, qdeg, qdat, out);
}